// Round 3
// baseline (2454.423 us; speedup 1.0000x reference)
//
#include <hip/hip_runtime.h>
#include <hip/hip_bf16.h>

// GATPredictor: x(8,12,1500) f32 -> 2-layer LSTM(hid64) per (b,n) sequence ->
// 2x GAT(4 heads x 16) over N=1500 graph -> linear head (3) -> (B,3,N) f32.
// ALL float tensors are float32 (reference declares jnp.float32 throughout).
// Intermediates live in d_ws (needs ~6.6 MB).

#define BN 12000
#define NNODE 1500
#define NB 8
#define TT 12

__device__ __forceinline__ float sigf(float v) { return 1.f / (1.f + __expf(-v)); }

__device__ __forceinline__ float tanhf_(float v) {
    float a = fabsf(v);
    float e = __expf(-2.f * a);
    float r = (1.f - e) / (1.f + e);
    return v < 0.f ? -r : r;
}

// ---------------------------------------------------------------------------
// Fused 2-layer LSTM. Block = 64 sequences (lane = seq), 8 waves; wave w owns
// hidden dims w*8..w*8+7 (all 4 gates). Weights are wave-uniform -> scalar
// loads; per-lane h vectors in registers. h exchanged via LDS with rotation
// addressing (d+lane)&63 (bank-conflict free, no padding => exactly 64 KB).
// c state kept in LDS [d][lane] (q loop indexes it dynamically).
// ---------------------------------------------------------------------------
__global__ __launch_bounds__(512, 2) void lstm_kernel(
    const float* __restrict__ x,
    const float* __restrict__ Wih0, const float* __restrict__ Whh0,
    const float* __restrict__ bih0, const float* __restrict__ bhh0,
    const float* __restrict__ Wih1, const float* __restrict__ Whh1,
    const float* __restrict__ bih1, const float* __restrict__ bhh1,
    float* __restrict__ hfin)
{
    __shared__ float h0s[4096];
    __shared__ float h1s[4096];
    __shared__ float c0s[4096];
    __shared__ float c1s[4096];

    int tid  = threadIdx.x;
    int w    = __builtin_amdgcn_readfirstlane(tid >> 6);
    int lane = tid & 63;
    int w8   = w * 8;
    int s    = blockIdx.x * 64 + lane;
    bool vs  = s < BN;
    int sc   = vs ? s : 0;
    int bb   = sc / NNODE, nn = sc % NNODE;
    const float* xp = x + (bb * (TT * NNODE) + nn);

    for (int e = tid; e < 4096; e += 512) {
        h0s[e] = 0.f; h1s[e] = 0.f; c0s[e] = 0.f; c1s[e] = 0.f;
    }
    __syncthreads();

    for (int t = 0; t < TT; ++t) {
        // ---- layer 0 ----
        float hA[64];
        #pragma unroll
        for (int k = 0; k < 64; ++k) hA[k] = h0s[(lane << 6) + ((k + lane) & 63)];
        __syncthreads();   // all reads of old h0 done before anyone writes new h0
        float xt = vs ? xp[t * NNODE] : 0.f;
        for (int q = 0; q < 8; ++q) {
            int d = w8 + q;
            float ai = fmaf(Wih0[d],       xt, bih0[d]       + bhh0[d]);
            float af = fmaf(Wih0[64 + d],  xt, bih0[64 + d]  + bhh0[64 + d]);
            float ag = fmaf(Wih0[128 + d], xt, bih0[128 + d] + bhh0[128 + d]);
            float ao = fmaf(Wih0[192 + d], xt, bih0[192 + d] + bhh0[192 + d]);
            const float* wi = Whh0 + (d << 6);
            const float* wf = Whh0 + ((64 + d) << 6);
            const float* wg = Whh0 + ((128 + d) << 6);
            const float* wo = Whh0 + ((192 + d) << 6);
            #pragma unroll
            for (int k = 0; k < 64; ++k) {
                float hv = hA[k];
                ai = fmaf(wi[k], hv, ai);
                af = fmaf(wf[k], hv, af);
                ag = fmaf(wg[k], hv, ag);
                ao = fmaf(wo[k], hv, ao);
            }
            float c = c0s[(d << 6) + lane];
            c = sigf(af) * c + sigf(ai) * tanhf_(ag);
            c0s[(d << 6) + lane] = c;
            h0s[(lane << 6) + ((d + lane) & 63)] = sigf(ao) * tanhf_(c);
        }
        __syncthreads();   // new h0 complete

        // ---- layer 1 ----
        float hB[64];
        #pragma unroll
        for (int k = 0; k < 64; ++k) {
            hA[k] = h0s[(lane << 6) + ((k + lane) & 63)];
            hB[k] = h1s[(lane << 6) + ((k + lane) & 63)];
        }
        __syncthreads();   // all reads of old h1 done before anyone writes new h1
        for (int q = 0; q < 8; ++q) {
            int d = w8 + q;
            float ai = bih1[d]       + bhh1[d];
            float af = bih1[64 + d]  + bhh1[64 + d];
            float ag = bih1[128 + d] + bhh1[128 + d];
            float ao = bih1[192 + d] + bhh1[192 + d];
            const float* ui = Wih1 + (d << 6);
            const float* uf = Wih1 + ((64 + d) << 6);
            const float* ug = Wih1 + ((128 + d) << 6);
            const float* uo = Wih1 + ((192 + d) << 6);
            const float* vi = Whh1 + (d << 6);
            const float* vf = Whh1 + ((64 + d) << 6);
            const float* vg = Whh1 + ((128 + d) << 6);
            const float* vo = Whh1 + ((192 + d) << 6);
            #pragma unroll
            for (int k = 0; k < 64; ++k) {
                float ha = hA[k], hb = hB[k];
                ai = fmaf(ui[k], ha, ai); ai = fmaf(vi[k], hb, ai);
                af = fmaf(uf[k], ha, af); af = fmaf(vf[k], hb, af);
                ag = fmaf(ug[k], ha, ag); ag = fmaf(vg[k], hb, ag);
                ao = fmaf(uo[k], ha, ao); ao = fmaf(vo[k], hb, ao);
            }
            float c = c1s[(d << 6) + lane];
            c = sigf(af) * c + sigf(ai) * tanhf_(ag);
            c1s[(d << 6) + lane] = c;
            h1s[(lane << 6) + ((d + lane) & 63)] = sigf(ao) * tanhf_(c);
        }
        __syncthreads();   // new h1 complete for next step
    }

    if (vs) {
        #pragma unroll
        for (int q = 0; q < 8; ++q) {
            int d = w8 + q;
            hfin[s * 64 + d] = h1s[(lane << 6) + ((d + lane) & 63)];
        }
    }
}

// ---------------------------------------------------------------------------
// GAT projection: hp = h @ W.T, e_src = <hp, asrc>, e_dst = <hp, adst>.
// Block = 4 nodes (one per wave); W staged transposed in LDS.
// ---------------------------------------------------------------------------
__global__ __launch_bounds__(256) void gat_prep(
    const float* __restrict__ hin, const float* __restrict__ W,
    const float* __restrict__ asrc, const float* __restrict__ adst,
    float* __restrict__ hp, float* __restrict__ esrc, float* __restrict__ edst)
{
    __shared__ float Wt[4096];    // [k][out]
    __shared__ float av[128];     // asrc | adst
    __shared__ float hrow[256];   // [wave][k]

    int tid = threadIdx.x;
    for (int e = tid; e < 4096; e += 256) {
        // Wt[k*64+row] = W[row*64+k]; consecutive threads -> consecutive LDS
        Wt[e] = W[(e & 63) * 64 + (e >> 6)];
    }
    if (tid < 64) { av[tid] = asrc[tid]; av[64 + tid] = adst[tid]; }
    int wv = tid >> 6, ln = tid & 63;
    int s = blockIdx.x * 4 + wv;
    hrow[wv * 64 + ln] = hin[s * 64 + ln];
    __syncthreads();

    float acc = 0.f;
    #pragma unroll
    for (int k = 0; k < 64; ++k) acc = fmaf(hrow[wv * 64 + k], Wt[k * 64 + ln], acc);
    hp[s * 64 + ln] = acc;

    float ts = acc * av[ln];
    float td = acc * av[64 + ln];
    #pragma unroll
    for (int m = 1; m <= 8; m <<= 1) {
        ts += __shfl_xor(ts, m);
        td += __shfl_xor(td, m);
    }
    if ((ln & 15) == 0) {
        esrc[s * 4 + (ln >> 4)] = ts;
        edst[s * 4 + (ln >> 4)] = td;
    }
}

// ---------------------------------------------------------------------------
// GAT aggregation, fused softmax (no max subtraction needed: |e| is O(1)):
// ho[b,i,h,:] = relu( sum_j mask*exp(leaky(es_i+ed_j)) * hp[b,j,h,:] / S ).
// Block = 32 target nodes i (8 waves x 4 i). Lane = (jsub 0..7, head 0..3,
// d-half 0..1); hp tiles (128 j) staged in LDS with pad-68 stride.
// ---------------------------------------------------------------------------
__global__ __launch_bounds__(512) void gat_agg(
    const float* __restrict__ hp, const float* __restrict__ esrc,
    const float* __restrict__ edst, const int* __restrict__ adj,
    float* __restrict__ hout)
{
    __shared__ float hp_lds[128 * 68];
    __shared__ float ed_lds[128 * 4];

    int tid  = threadIdx.x;
    int b    = blockIdx.x / 47;
    int i0   = (blockIdx.x % 47) * 32;
    int wv   = tid >> 6, ln = tid & 63;
    int jsub = ln >> 3;
    int sub  = ln & 7;
    int hh   = sub >> 1;
    int dh   = sub & 1;
    int ib   = i0 + wv * 4;

    float es[4], S[4], acc[4][8];
    int arow0[4];
    #pragma unroll
    for (int ii = 0; ii < 4; ++ii) {
        int i = min(ib + ii, NNODE - 1);
        es[ii] = esrc[(b * NNODE + i) * 4 + hh];
        arow0[ii] = i * NNODE;
        S[ii] = 0.f;
        #pragma unroll
        for (int q = 0; q < 8; ++q) acc[ii][q] = 0.f;
    }

    const float4* hp4 = (const float4*)hp + (long)b * NNODE * 16;
    const float4* ed4 = (const float4*)edst + b * NNODE;

    for (int j0 = 0; j0 < NNODE; j0 += 128) {
        int JTc = min(128, NNODE - j0);
        for (int g = tid; g < JTc * 16; g += 512) {
            int jl = g >> 4, dq = g & 15;
            float4 v = hp4[(j0 + jl) * 16 + dq];
            *(float4*)&hp_lds[jl * 68 + dq * 4] = v;
        }
        if (tid < JTc) {
            float4 e4 = ed4[j0 + tid];
            *(float4*)&ed_lds[tid * 4] = e4;
        }
        __syncthreads();

        for (int jj = 0; jj < 128; jj += 8) {
            int jl = jj + jsub;
            bool vj = jl < JTc;
            int jc = vj ? jl : 0;
            float ed = ed_lds[jc * 4 + hh];
            // fragment for THIS head: dims hh*16 + dh*8 + 0..7
            const float4* hr = (const float4*)&hp_lds[jc * 68 + hh * 16 + dh * 8];
            float4 u0 = hr[0], u1 = hr[1];
            int jg = j0 + jc;
            #pragma unroll
            for (int ii = 0; ii < 4; ++ii) {
                int a = adj[arow0[ii] + jg];
                float e = es[ii] + ed;
                e = fmaxf(e, 0.2f * e);               // LeakyReLU(0.2)
                float p = (vj && a > 0) ? __expf(e) : 0.f;
                S[ii] += p;
                acc[ii][0] = fmaf(p, u0.x, acc[ii][0]);
                acc[ii][1] = fmaf(p, u0.y, acc[ii][1]);
                acc[ii][2] = fmaf(p, u0.z, acc[ii][2]);
                acc[ii][3] = fmaf(p, u0.w, acc[ii][3]);
                acc[ii][4] = fmaf(p, u1.x, acc[ii][4]);
                acc[ii][5] = fmaf(p, u1.y, acc[ii][5]);
                acc[ii][6] = fmaf(p, u1.z, acc[ii][6]);
                acc[ii][7] = fmaf(p, u1.w, acc[ii][7]);
            }
        }
        __syncthreads();
    }

    // reduce over the 8 j-subgroups (lane bits 3..5)
    #pragma unroll
    for (int ii = 0; ii < 4; ++ii) {
        #pragma unroll
        for (int m = 8; m <= 32; m <<= 1) {
            S[ii] += __shfl_xor(S[ii], m);
            #pragma unroll
            for (int q = 0; q < 8; ++q) acc[ii][q] += __shfl_xor(acc[ii][q], m);
        }
    }

    if (jsub == 0) {
        #pragma unroll
        for (int ii = 0; ii < 4; ++ii) {
            int i = ib + ii;
            if (i < NNODE) {
                float rs = 1.f / S[ii];
                float* dst = &hout[((b * NNODE + i) << 6) + hh * 16 + dh * 8];
                float4 o0, o1;
                o0.x = fmaxf(acc[ii][0] * rs, 0.f);
                o0.y = fmaxf(acc[ii][1] * rs, 0.f);
                o0.z = fmaxf(acc[ii][2] * rs, 0.f);
                o0.w = fmaxf(acc[ii][3] * rs, 0.f);
                o1.x = fmaxf(acc[ii][4] * rs, 0.f);
                o1.y = fmaxf(acc[ii][5] * rs, 0.f);
                o1.z = fmaxf(acc[ii][6] * rs, 0.f);
                o1.w = fmaxf(acc[ii][7] * rs, 0.f);
                *(float4*)dst = o0;
                *(float4*)(dst + 4) = o1;
            }
        }
    }
}

// ---------------------------------------------------------------------------
// Output head: out[b,o,n] = h2[b,n,:] . out_W[o,:] + out_b[o]
// ---------------------------------------------------------------------------
__global__ __launch_bounds__(256) void out_kernel(
    const float* __restrict__ h, const float* __restrict__ oW,
    const float* __restrict__ ob, float* __restrict__ out)
{
    int idx = blockIdx.x * 256 + threadIdx.x;
    if (idx >= NB * 3 * NNODE) return;
    int b = idx / (3 * NNODE);
    int r = idx % (3 * NNODE);
    int o = r / NNODE;
    int n = r % NNODE;
    const float* hr = h + (b * NNODE + n) * 64;
    float acc = ob[o];
    #pragma unroll
    for (int k = 0; k < 64; ++k) acc = fmaf(hr[k], oW[o * 64 + k], acc);
    out[idx] = acc;
}

// ---------------------------------------------------------------------------
extern "C" void kernel_launch(void* const* d_in, const int* in_sizes, int n_in,
                              void* d_out, int out_size, void* d_ws, size_t ws_size,
                              hipStream_t stream) {
    const float* x    = (const float*)d_in[0];
    const int*   adj  = (const int*)d_in[1];
    const float* Wih0 = (const float*)d_in[2];
    const float* Whh0 = (const float*)d_in[3];
    const float* bih0 = (const float*)d_in[4];
    const float* bhh0 = (const float*)d_in[5];
    const float* Wih1 = (const float*)d_in[6];
    const float* Whh1 = (const float*)d_in[7];
    const float* bih1 = (const float*)d_in[8];
    const float* bhh1 = (const float*)d_in[9];
    const float* g0W  = (const float*)d_in[10];
    const float* g0s  = (const float*)d_in[11];
    const float* g0d  = (const float*)d_in[12];
    const float* g1W  = (const float*)d_in[13];
    const float* g1s  = (const float*)d_in[14];
    const float* g1d  = (const float*)d_in[15];
    const float* oW   = (const float*)d_in[16];
    const float* ob   = (const float*)d_in[17];

    float* ws   = (float*)d_ws;
    float* bufh = ws;                 // 768000 floats: h between stages
    float* hp   = ws + 768000;        // 768000
    float* esr  = ws + 1536000;       // 48000
    float* eds  = ws + 1584000;       // 48000

    lstm_kernel<<<188, 512, 0, stream>>>(x, Wih0, Whh0, bih0, bhh0,
                                         Wih1, Whh1, bih1, bhh1, bufh);
    gat_prep<<<3000, 256, 0, stream>>>(bufh, g0W, g0s, g0d, hp, esr, eds);
    gat_agg<<<376, 512, 0, stream>>>(hp, esr, eds, adj, bufh);
    gat_prep<<<3000, 256, 0, stream>>>(bufh, g1W, g1s, g1d, hp, esr, eds);
    gat_agg<<<376, 512, 0, stream>>>(hp, esr, eds, adj, bufh);
    out_kernel<<<141, 256, 0, stream>>>(bufh, oW, ob, (float*)d_out);
}

// Round 4
// 545.962 us; speedup vs baseline: 4.4956x; 4.4956x over previous
//
#include <hip/hip_runtime.h>
#include <hip/hip_bf16.h>

// GATPredictor: x(8,12,1500) f32 -> 2-layer LSTM(hid64) per (b,n) sequence ->
// 2x GAT(4 heads x 16) over N=1500 graph -> linear head (3) -> (B,3,N) f32.
// LSTM now runs on MFMA (bf16 in / f32 accum): per step it is a
// 12000x256x{64,128} GEMM. GAT + head remain f32 (unchanged from round 3).

#define BN 12000
#define NNODE 1500
#define NB 8
#define TT 12

typedef __bf16 bf16x8 __attribute__((ext_vector_type(8)));
typedef __bf16 bf16x4 __attribute__((ext_vector_type(4)));
typedef float  f32x4  __attribute__((ext_vector_type(4)));

__device__ __forceinline__ float sigf(float v) { return 1.f / (1.f + __expf(-v)); }

__device__ __forceinline__ float tanhf_(float v) {
    float a = fabsf(v);
    float e = __expf(-2.f * a);
    float r = (1.f - e) / (1.f + e);
    return v < 0.f ? -r : r;
}

// ---------------------------------------------------------------------------
// Convert LSTM matmul weights to bf16 in ws.
// wb0[g*64+k]  = Whh0[g][k]                       (256 x 64)
// wb1[g*128+k] = k<64 ? Wih1[g][k] : Whh1[g][k-64] (256 x 128, concat K)
// ---------------------------------------------------------------------------
__global__ __launch_bounds__(256) void wconv_kernel(
    const float* __restrict__ Whh0, const float* __restrict__ Wih1,
    const float* __restrict__ Whh1,
    __bf16* __restrict__ wb0, __bf16* __restrict__ wb1)
{
    int i = blockIdx.x * 256 + threadIdx.x;
    if (i < 16384) {
        wb0[i] = (__bf16)Whh0[i];
    } else if (i < 49152) {
        int j = i - 16384;
        int g = j >> 7, k = j & 127;
        wb1[j] = (__bf16)(k < 64 ? Wih1[(g << 6) + k] : Whh1[(g << 6) + k - 64]);
    }
}

// ---------------------------------------------------------------------------
// MFMA 2-layer LSTM. Block = 64 seqs, 512 thr (8 waves). Wave w owns gates
// [32w,32w+32) as two 16-wide n-tiles; B-fragments (weights) live in VGPRs
// for the whole kernel. h0/h1 in LDS as bf16 [64 seq][72] (pad->conflict-free
// b128 A-frag reads). Gate preacts round-trip LDS transposed G_t[n][72]
// (C-frag regs = 4 consecutive m -> one b64 write). Bias + Wih0*x_t folded
// into the accumulator init. c-state in registers (thread owns fixed
// (m=lane, d=8w..8w+7)). 4 barriers/step.
// ---------------------------------------------------------------------------
__global__ __launch_bounds__(512, 2) void lstm_mfma(
    const float* __restrict__ x,
    const float* __restrict__ Wih0,
    const float* __restrict__ bih0, const float* __restrict__ bhh0,
    const float* __restrict__ bih1, const float* __restrict__ bhh1,
    const __bf16* __restrict__ wb0, const __bf16* __restrict__ wb1,
    float* __restrict__ hfin)
{
    __shared__ __align__(16) __bf16 Gts[256 * 72];   // 36 KB
    __shared__ __align__(16) __bf16 h0s[64 * 72];    // 9 KB
    __shared__ __align__(16) __bf16 h1s[64 * 72];    // 9 KB
    __shared__ __align__(16) float  xls[TT * 64];    // 3 KB

    int tid  = threadIdx.x;
    int w    = __builtin_amdgcn_readfirstlane(tid >> 6);
    int lane = tid & 63;
    int l15  = lane & 15;
    int qd   = lane >> 4;

    // zero h state
    for (int e = tid; e < (64 * 72) / 8; e += 512) {
        uint4 z = {0u, 0u, 0u, 0u};
        ((uint4*)h0s)[e] = z;
        ((uint4*)h1s)[e] = z;
    }
    // stage x tile: xls[t][m]
    for (int e = tid; e < TT * 64; e += 512) {
        int t = e >> 6, m = e & 63;
        int s = blockIdx.x * 64 + m;
        float v = 0.f;
        if (s < BN) {
            int bb = s / NNODE, nn = s - bb * NNODE;
            v = x[bb * (TT * NNODE) + t * NNODE + nn];
        }
        xls[t * 64 + m] = v;
    }

    // persistent weight fragments + per-gate scalars (lane-indexed)
    bf16x8 B0[2][2], B1[2][4];
    float b0v[2], b1v[2], w0v[2];
    #pragma unroll
    for (int lt = 0; lt < 2; ++lt) {
        int g = 32 * w + 16 * lt + l15;
        b0v[lt] = bih0[g] + bhh0[g];
        b1v[lt] = bih1[g] + bhh1[g];
        w0v[lt] = Wih0[g];
        #pragma unroll
        for (int kt = 0; kt < 2; ++kt)
            B0[lt][kt] = *(const bf16x8*)&wb0[g * 64 + 32 * kt + 8 * qd];
        #pragma unroll
        for (int kt = 0; kt < 4; ++kt)
            B1[lt][kt] = *(const bf16x8*)&wb1[g * 128 + 32 * kt + 8 * qd];
    }

    float c0r[8], c1r[8];
    #pragma unroll
    for (int j = 0; j < 8; ++j) { c0r[j] = 0.f; c1r[j] = 0.f; }
    int sseq = blockIdx.x * 64 + lane;

    __syncthreads();

    for (int t = 0; t < TT; ++t) {
        // ================= Layer 0: MFMA =================
        {
            bf16x8 af[4][2];
            #pragma unroll
            for (int mt = 0; mt < 4; ++mt)
                #pragma unroll
                for (int kt = 0; kt < 2; ++kt)
                    af[mt][kt] = *(bf16x8*)&h0s[(16 * mt + l15) * 72 + 32 * kt + 8 * qd];

            f32x4 acc[4][2];
            #pragma unroll
            for (int mt = 0; mt < 4; ++mt) {
                f32x4 xv = *(f32x4*)&xls[t * 64 + 16 * mt + 4 * qd];
                #pragma unroll
                for (int lt = 0; lt < 2; ++lt)
                    #pragma unroll
                    for (int r = 0; r < 4; ++r)
                        acc[mt][lt][r] = fmaf(w0v[lt], xv[r], b0v[lt]);
            }
            #pragma unroll
            for (int kt = 0; kt < 2; ++kt)
                #pragma unroll
                for (int mt = 0; mt < 4; ++mt)
                    #pragma unroll
                    for (int lt = 0; lt < 2; ++lt)
                        acc[mt][lt] = __builtin_amdgcn_mfma_f32_16x16x32_bf16(
                            af[mt][kt], B0[lt][kt], acc[mt][lt], 0, 0, 0);
            // G_t[n][m] bf16 (C-frag regs are 4 consecutive m)
            #pragma unroll
            for (int mt = 0; mt < 4; ++mt)
                #pragma unroll
                for (int lt = 0; lt < 2; ++lt) {
                    bf16x4 p;
                    #pragma unroll
                    for (int r = 0; r < 4; ++r) p[r] = (__bf16)acc[mt][lt][r];
                    *(bf16x4*)&Gts[(32 * w + 16 * lt + l15) * 72 + 16 * mt + 4 * qd] = p;
                }
        }
        __syncthreads();
        // ================= Layer 0: gates =================
        {
            float hnew[8];
            #pragma unroll
            for (int j = 0; j < 8; ++j) {
                int d = 8 * w + j;
                float gi = (float)Gts[d * 72 + lane];
                float gf = (float)Gts[(64 + d) * 72 + lane];
                float gg = (float)Gts[(128 + d) * 72 + lane];
                float go = (float)Gts[(192 + d) * 72 + lane];
                float c = sigf(gf) * c0r[j] + sigf(gi) * tanhf_(gg);
                c0r[j] = c;
                hnew[j] = sigf(go) * tanhf_(c);
            }
            bf16x8 p;
            #pragma unroll
            for (int j = 0; j < 8; ++j) p[j] = (__bf16)hnew[j];
            *(bf16x8*)&h0s[lane * 72 + 8 * w] = p;
        }
        __syncthreads();
        // ================= Layer 1: MFMA (K=128: h0|h1) =================
        {
            bf16x8 af[4][4];
            #pragma unroll
            for (int mt = 0; mt < 4; ++mt) {
                #pragma unroll
                for (int kt = 0; kt < 2; ++kt)
                    af[mt][kt] = *(bf16x8*)&h0s[(16 * mt + l15) * 72 + 32 * kt + 8 * qd];
                #pragma unroll
                for (int kt = 2; kt < 4; ++kt)
                    af[mt][kt] = *(bf16x8*)&h1s[(16 * mt + l15) * 72 + 32 * (kt - 2) + 8 * qd];
            }
            f32x4 acc[4][2];
            #pragma unroll
            for (int mt = 0; mt < 4; ++mt)
                #pragma unroll
                for (int lt = 0; lt < 2; ++lt)
                    #pragma unroll
                    for (int r = 0; r < 4; ++r) acc[mt][lt][r] = b1v[lt];
            #pragma unroll
            for (int kt = 0; kt < 4; ++kt)
                #pragma unroll
                for (int mt = 0; mt < 4; ++mt)
                    #pragma unroll
                    for (int lt = 0; lt < 2; ++lt)
                        acc[mt][lt] = __builtin_amdgcn_mfma_f32_16x16x32_bf16(
                            af[mt][kt], B1[lt][kt], acc[mt][lt], 0, 0, 0);
            #pragma unroll
            for (int mt = 0; mt < 4; ++mt)
                #pragma unroll
                for (int lt = 0; lt < 2; ++lt) {
                    bf16x4 p;
                    #pragma unroll
                    for (int r = 0; r < 4; ++r) p[r] = (__bf16)acc[mt][lt][r];
                    *(bf16x4*)&Gts[(32 * w + 16 * lt + l15) * 72 + 16 * mt + 4 * qd] = p;
                }
        }
        __syncthreads();
        // ================= Layer 1: gates =================
        {
            float hnew[8];
            #pragma unroll
            for (int j = 0; j < 8; ++j) {
                int d = 8 * w + j;
                float gi = (float)Gts[d * 72 + lane];
                float gf = (float)Gts[(64 + d) * 72 + lane];
                float gg = (float)Gts[(128 + d) * 72 + lane];
                float go = (float)Gts[(192 + d) * 72 + lane];
                float c = sigf(gf) * c1r[j] + sigf(gi) * tanhf_(gg);
                c1r[j] = c;
                hnew[j] = sigf(go) * tanhf_(c);
            }
            bf16x8 p;
            #pragma unroll
            for (int j = 0; j < 8; ++j) p[j] = (__bf16)hnew[j];
            *(bf16x8*)&h1s[lane * 72 + 8 * w] = p;
            if (t == TT - 1 && sseq < BN) {   // final hidden in f32 for GAT
                f32x4 o0, o1;
                o0[0] = hnew[0]; o0[1] = hnew[1]; o0[2] = hnew[2]; o0[3] = hnew[3];
                o1[0] = hnew[4]; o1[1] = hnew[5]; o1[2] = hnew[6]; o1[3] = hnew[7];
                *(f32x4*)&hfin[sseq * 64 + 8 * w]     = o0;
                *(f32x4*)&hfin[sseq * 64 + 8 * w + 4] = o1;
            }
        }
        __syncthreads();
    }
}

// ---------------------------------------------------------------------------
// GAT projection: hp = h @ W.T, e_src = <hp, asrc>, e_dst = <hp, adst>.
// Block = 4 nodes (one per wave); W staged transposed in LDS.
// ---------------------------------------------------------------------------
__global__ __launch_bounds__(256) void gat_prep(
    const float* __restrict__ hin, const float* __restrict__ W,
    const float* __restrict__ asrc, const float* __restrict__ adst,
    float* __restrict__ hp, float* __restrict__ esrc, float* __restrict__ edst)
{
    __shared__ float Wt[4096];    // [k][out]
    __shared__ float av[128];     // asrc | adst
    __shared__ float hrow[256];   // [wave][k]

    int tid = threadIdx.x;
    for (int e = tid; e < 4096; e += 256) {
        Wt[e] = W[(e & 63) * 64 + (e >> 6)];
    }
    if (tid < 64) { av[tid] = asrc[tid]; av[64 + tid] = adst[tid]; }
    int wv = tid >> 6, ln = tid & 63;
    int s = blockIdx.x * 4 + wv;
    hrow[wv * 64 + ln] = hin[s * 64 + ln];
    __syncthreads();

    float acc = 0.f;
    #pragma unroll
    for (int k = 0; k < 64; ++k) acc = fmaf(hrow[wv * 64 + k], Wt[k * 64 + ln], acc);
    hp[s * 64 + ln] = acc;

    float ts = acc * av[ln];
    float td = acc * av[64 + ln];
    #pragma unroll
    for (int m = 1; m <= 8; m <<= 1) {
        ts += __shfl_xor(ts, m);
        td += __shfl_xor(td, m);
    }
    if ((ln & 15) == 0) {
        esrc[s * 4 + (ln >> 4)] = ts;
        edst[s * 4 + (ln >> 4)] = td;
    }
}

// ---------------------------------------------------------------------------
// GAT aggregation, fused single-pass softmax (|e| is O(1): no max-sub).
// ---------------------------------------------------------------------------
__global__ __launch_bounds__(512) void gat_agg(
    const float* __restrict__ hp, const float* __restrict__ esrc,
    const float* __restrict__ edst, const int* __restrict__ adj,
    float* __restrict__ hout)
{
    __shared__ float hp_lds[128 * 68];
    __shared__ float ed_lds[128 * 4];

    int tid  = threadIdx.x;
    int b    = blockIdx.x / 47;
    int i0   = (blockIdx.x % 47) * 32;
    int wv   = tid >> 6, ln = tid & 63;
    int jsub = ln >> 3;
    int sub  = ln & 7;
    int hh   = sub >> 1;
    int dh   = sub & 1;
    int ib   = i0 + wv * 4;

    float es[4], S[4], acc[4][8];
    int arow0[4];
    #pragma unroll
    for (int ii = 0; ii < 4; ++ii) {
        int i = min(ib + ii, NNODE - 1);
        es[ii] = esrc[(b * NNODE + i) * 4 + hh];
        arow0[ii] = i * NNODE;
        S[ii] = 0.f;
        #pragma unroll
        for (int q = 0; q < 8; ++q) acc[ii][q] = 0.f;
    }

    const float4* hp4 = (const float4*)hp + (long)b * NNODE * 16;
    const float4* ed4 = (const float4*)edst + b * NNODE;

    for (int j0 = 0; j0 < NNODE; j0 += 128) {
        int JTc = min(128, NNODE - j0);
        for (int g = tid; g < JTc * 16; g += 512) {
            int jl = g >> 4, dq = g & 15;
            float4 v = hp4[(j0 + jl) * 16 + dq];
            *(float4*)&hp_lds[jl * 68 + dq * 4] = v;
        }
        if (tid < JTc) {
            float4 e4 = ed4[j0 + tid];
            *(float4*)&ed_lds[tid * 4] = e4;
        }
        __syncthreads();

        for (int jj = 0; jj < 128; jj += 8) {
            int jl = jj + jsub;
            bool vj = jl < JTc;
            int jc = vj ? jl : 0;
            float ed = ed_lds[jc * 4 + hh];
            const float4* hr = (const float4*)&hp_lds[jc * 68 + hh * 16 + dh * 8];
            float4 u0 = hr[0], u1 = hr[1];
            int jg = j0 + jc;
            #pragma unroll
            for (int ii = 0; ii < 4; ++ii) {
                int a = adj[arow0[ii] + jg];
                float e = es[ii] + ed;
                e = fmaxf(e, 0.2f * e);               // LeakyReLU(0.2)
                float p = (vj && a > 0) ? __expf(e) : 0.f;
                S[ii] += p;
                acc[ii][0] = fmaf(p, u0.x, acc[ii][0]);
                acc[ii][1] = fmaf(p, u0.y, acc[ii][1]);
                acc[ii][2] = fmaf(p, u0.z, acc[ii][2]);
                acc[ii][3] = fmaf(p, u0.w, acc[ii][3]);
                acc[ii][4] = fmaf(p, u1.x, acc[ii][4]);
                acc[ii][5] = fmaf(p, u1.y, acc[ii][5]);
                acc[ii][6] = fmaf(p, u1.z, acc[ii][6]);
                acc[ii][7] = fmaf(p, u1.w, acc[ii][7]);
            }
        }
        __syncthreads();
    }

    #pragma unroll
    for (int ii = 0; ii < 4; ++ii) {
        #pragma unroll
        for (int m = 8; m <= 32; m <<= 1) {
            S[ii] += __shfl_xor(S[ii], m);
            #pragma unroll
            for (int q = 0; q < 8; ++q) acc[ii][q] += __shfl_xor(acc[ii][q], m);
        }
    }

    if (jsub == 0) {
        #pragma unroll
        for (int ii = 0; ii < 4; ++ii) {
            int i = ib + ii;
            if (i < NNODE) {
                float rs = 1.f / S[ii];
                float* dst = &hout[((b * NNODE + i) << 6) + hh * 16 + dh * 8];
                float4 o0, o1;
                o0.x = fmaxf(acc[ii][0] * rs, 0.f);
                o0.y = fmaxf(acc[ii][1] * rs, 0.f);
                o0.z = fmaxf(acc[ii][2] * rs, 0.f);
                o0.w = fmaxf(acc[ii][3] * rs, 0.f);
                o1.x = fmaxf(acc[ii][4] * rs, 0.f);
                o1.y = fmaxf(acc[ii][5] * rs, 0.f);
                o1.z = fmaxf(acc[ii][6] * rs, 0.f);
                o1.w = fmaxf(acc[ii][7] * rs, 0.f);
                *(float4*)dst = o0;
                *(float4*)(dst + 4) = o1;
            }
        }
    }
}

// ---------------------------------------------------------------------------
// Output head: out[b,o,n] = h2[b,n,:] . out_W[o,:] + out_b[o]
// ---------------------------------------------------------------------------
__global__ __launch_bounds__(256) void out_kernel(
    const float* __restrict__ h, const float* __restrict__ oW,
    const float* __restrict__ ob, float* __restrict__ out)
{
    int idx = blockIdx.x * 256 + threadIdx.x;
    if (idx >= NB * 3 * NNODE) return;
    int b = idx / (3 * NNODE);
    int r = idx % (3 * NNODE);
    int o = r / NNODE;
    int n = r % NNODE;
    const float* hr = h + (b * NNODE + n) * 64;
    float acc = ob[o];
    #pragma unroll
    for (int k = 0; k < 64; ++k) acc = fmaf(hr[k], oW[o * 64 + k], acc);
    out[idx] = acc;
}

// ---------------------------------------------------------------------------
extern "C" void kernel_launch(void* const* d_in, const int* in_sizes, int n_in,
                              void* d_out, int out_size, void* d_ws, size_t ws_size,
                              hipStream_t stream) {
    const float* x    = (const float*)d_in[0];
    const int*   adj  = (const int*)d_in[1];
    const float* Wih0 = (const float*)d_in[2];
    const float* Whh0 = (const float*)d_in[3];
    const float* bih0 = (const float*)d_in[4];
    const float* bhh0 = (const float*)d_in[5];
    const float* Wih1 = (const float*)d_in[6];
    const float* Whh1 = (const float*)d_in[7];
    const float* bih1 = (const float*)d_in[8];
    const float* bhh1 = (const float*)d_in[9];
    const float* g0W  = (const float*)d_in[10];
    const float* g0s  = (const float*)d_in[11];
    const float* g0d  = (const float*)d_in[12];
    const float* g1W  = (const float*)d_in[13];
    const float* g1s  = (const float*)d_in[14];
    const float* g1d  = (const float*)d_in[15];
    const float* oW   = (const float*)d_in[16];
    const float* ob   = (const float*)d_in[17];

    float* ws   = (float*)d_ws;
    float* bufh = ws;                 // 768000 floats: h between stages
    float* hp   = ws + 768000;        // 768000
    float* esr  = ws + 1536000;       // 48000
    float* eds  = ws + 1584000;       // 48000
    __bf16* wb0 = (__bf16*)(ws + 1632000);   // 16384 bf16
    __bf16* wb1 = (__bf16*)(ws + 1640192);   // 32768 bf16

    wconv_kernel<<<192, 256, 0, stream>>>(Whh0, Wih1, Whh1, wb0, wb1);
    lstm_mfma<<<188, 512, 0, stream>>>(x, Wih0, bih0, bhh0, bih1, bhh1,
                                       wb0, wb1, bufh);
    gat_prep<<<3000, 256, 0, stream>>>(bufh, g0W, g0s, g0d, hp, esr, eds);
    gat_agg<<<376, 512, 0, stream>>>(hp, esr, eds, adj, bufh);
    gat_prep<<<3000, 256, 0, stream>>>(bufh, g1W, g1s, g1d, hp, esr, eds);
    gat_agg<<<376, 512, 0, stream>>>(hp, esr, eds, adj, bufh);
    out_kernel<<<141, 256, 0, stream>>>(bufh, oW, ob, (float*)d_out);
}

// Round 5
// 332.890 us; speedup vs baseline: 7.3731x; 1.6401x over previous
//
#include <hip/hip_runtime.h>
#include <hip/hip_bf16.h>

// GATPredictor: x(8,12,1500) f32 -> 2-layer LSTM(hid64) per (b,n) sequence ->
// 2x GAT(4 heads x 16) over N=1500 graph -> linear head (3) -> (B,3,N) f32.
// LSTM: MFMA bf16 (round 4, verified). GAT aggregation now flash-style MFMA:
// P computed in A-fragment layout in VALU, PV via mfma_f32_16x16x32_bf16,
// adjacency as a bitmask (built once, shared by both layers).

#define BN 12000
#define NNODE 1500
#define NB 8
#define TT 12
#define NPAD 1536   // padded j extent for hpT/esT/edT rows (12 tiles of 128)

typedef __bf16 bf16x8 __attribute__((ext_vector_type(8)));
typedef __bf16 bf16x4 __attribute__((ext_vector_type(4)));
typedef float  f32x4  __attribute__((ext_vector_type(4)));

__device__ __forceinline__ float sigf(float v) { return 1.f / (1.f + __expf(-v)); }

__device__ __forceinline__ float tanhf_(float v) {
    float a = fabsf(v);
    float e = __expf(-2.f * a);
    float r = (1.f - e) / (1.f + e);
    return v < 0.f ? -r : r;
}

// ---------------------------------------------------------------------------
// Convert LSTM matmul weights to bf16 in ws.
// ---------------------------------------------------------------------------
__global__ __launch_bounds__(256) void wconv_kernel(
    const float* __restrict__ Whh0, const float* __restrict__ Wih1,
    const float* __restrict__ Whh1,
    __bf16* __restrict__ wb0, __bf16* __restrict__ wb1)
{
    int i = blockIdx.x * 256 + threadIdx.x;
    if (i < 16384) {
        wb0[i] = (__bf16)Whh0[i];
    } else if (i < 49152) {
        int j = i - 16384;
        int g = j >> 7, k = j & 127;
        wb1[j] = (__bf16)(k < 64 ? Wih1[(g << 6) + k] : Whh1[(g << 6) + k - 64]);
    }
}

// ---------------------------------------------------------------------------
// Adjacency bitmask: mask[i][w] bits j in [w*32, w*32+32). 1504 rows x 48
// words; rows >=1500 and bits j>=1500 are zero. One wave per (i, 64-j chunk).
// ---------------------------------------------------------------------------
__global__ __launch_bounds__(256) void mask_kernel(
    const int* __restrict__ adj, unsigned int* __restrict__ mask)
{
    int idx  = blockIdx.x * 4 + (threadIdx.x >> 6);
    int lane = threadIdx.x & 63;
    int i  = idx / 24;
    int ch = idx - i * 24;
    if (i >= 1504) return;
    int j = ch * 64 + lane;
    int a = (i < NNODE && j < NNODE) ? adj[i * NNODE + j] : 0;
    unsigned long long m = __ballot(a > 0);
    if (lane == 0) *(unsigned long long*)&mask[i * 48 + ch * 2] = m;
}

// ---------------------------------------------------------------------------
// MFMA 2-layer LSTM (round-4 structure, verified absmax 2.4e-4).
// ---------------------------------------------------------------------------
__global__ __launch_bounds__(512, 2) void lstm_mfma(
    const float* __restrict__ x,
    const float* __restrict__ Wih0,
    const float* __restrict__ bih0, const float* __restrict__ bhh0,
    const float* __restrict__ bih1, const float* __restrict__ bhh1,
    const __bf16* __restrict__ wb0, const __bf16* __restrict__ wb1,
    float* __restrict__ hfin)
{
    __shared__ __align__(16) __bf16 Gts[256 * 72];   // 36 KB
    __shared__ __align__(16) __bf16 h0s[64 * 72];    // 9 KB
    __shared__ __align__(16) __bf16 h1s[64 * 72];    // 9 KB
    __shared__ __align__(16) float  xls[TT * 64];    // 3 KB

    int tid  = threadIdx.x;
    int w    = __builtin_amdgcn_readfirstlane(tid >> 6);
    int lane = tid & 63;
    int l15  = lane & 15;
    int qd   = lane >> 4;

    for (int e = tid; e < (64 * 72) / 8; e += 512) {
        uint4 z = {0u, 0u, 0u, 0u};
        ((uint4*)h0s)[e] = z;
        ((uint4*)h1s)[e] = z;
    }
    for (int e = tid; e < TT * 64; e += 512) {
        int t = e >> 6, m = e & 63;
        int s = blockIdx.x * 64 + m;
        float v = 0.f;
        if (s < BN) {
            int bb = s / NNODE, nn = s - bb * NNODE;
            v = x[bb * (TT * NNODE) + t * NNODE + nn];
        }
        xls[t * 64 + m] = v;
    }

    bf16x8 B0[2][2], B1[2][4];
    float b0v[2], b1v[2], w0v[2];
    #pragma unroll
    for (int lt = 0; lt < 2; ++lt) {
        int g = 32 * w + 16 * lt + l15;
        b0v[lt] = bih0[g] + bhh0[g];
        b1v[lt] = bih1[g] + bhh1[g];
        w0v[lt] = Wih0[g];
        #pragma unroll
        for (int kt = 0; kt < 2; ++kt)
            B0[lt][kt] = *(const bf16x8*)&wb0[g * 64 + 32 * kt + 8 * qd];
        #pragma unroll
        for (int kt = 0; kt < 4; ++kt)
            B1[lt][kt] = *(const bf16x8*)&wb1[g * 128 + 32 * kt + 8 * qd];
    }

    float c0r[8], c1r[8];
    #pragma unroll
    for (int j = 0; j < 8; ++j) { c0r[j] = 0.f; c1r[j] = 0.f; }
    int sseq = blockIdx.x * 64 + lane;

    __syncthreads();

    for (int t = 0; t < TT; ++t) {
        // Layer 0: MFMA
        {
            bf16x8 af[4][2];
            #pragma unroll
            for (int mt = 0; mt < 4; ++mt)
                #pragma unroll
                for (int kt = 0; kt < 2; ++kt)
                    af[mt][kt] = *(bf16x8*)&h0s[(16 * mt + l15) * 72 + 32 * kt + 8 * qd];

            f32x4 acc[4][2];
            #pragma unroll
            for (int mt = 0; mt < 4; ++mt) {
                f32x4 xv = *(f32x4*)&xls[t * 64 + 16 * mt + 4 * qd];
                #pragma unroll
                for (int lt = 0; lt < 2; ++lt)
                    #pragma unroll
                    for (int r = 0; r < 4; ++r)
                        acc[mt][lt][r] = fmaf(w0v[lt], xv[r], b0v[lt]);
            }
            #pragma unroll
            for (int kt = 0; kt < 2; ++kt)
                #pragma unroll
                for (int mt = 0; mt < 4; ++mt)
                    #pragma unroll
                    for (int lt = 0; lt < 2; ++lt)
                        acc[mt][lt] = __builtin_amdgcn_mfma_f32_16x16x32_bf16(
                            af[mt][kt], B0[lt][kt], acc[mt][lt], 0, 0, 0);
            #pragma unroll
            for (int mt = 0; mt < 4; ++mt)
                #pragma unroll
                for (int lt = 0; lt < 2; ++lt) {
                    bf16x4 p;
                    #pragma unroll
                    for (int r = 0; r < 4; ++r) p[r] = (__bf16)acc[mt][lt][r];
                    *(bf16x4*)&Gts[(32 * w + 16 * lt + l15) * 72 + 16 * mt + 4 * qd] = p;
                }
        }
        __syncthreads();
        // Layer 0: gates
        {
            float hnew[8];
            #pragma unroll
            for (int j = 0; j < 8; ++j) {
                int d = 8 * w + j;
                float gi = (float)Gts[d * 72 + lane];
                float gf = (float)Gts[(64 + d) * 72 + lane];
                float gg = (float)Gts[(128 + d) * 72 + lane];
                float go = (float)Gts[(192 + d) * 72 + lane];
                float c = sigf(gf) * c0r[j] + sigf(gi) * tanhf_(gg);
                c0r[j] = c;
                hnew[j] = sigf(go) * tanhf_(c);
            }
            bf16x8 p;
            #pragma unroll
            for (int j = 0; j < 8; ++j) p[j] = (__bf16)hnew[j];
            *(bf16x8*)&h0s[lane * 72 + 8 * w] = p;
        }
        __syncthreads();
        // Layer 1: MFMA (K=128: h0|h1)
        {
            bf16x8 af[4][4];
            #pragma unroll
            for (int mt = 0; mt < 4; ++mt) {
                #pragma unroll
                for (int kt = 0; kt < 2; ++kt)
                    af[mt][kt] = *(bf16x8*)&h0s[(16 * mt + l15) * 72 + 32 * kt + 8 * qd];
                #pragma unroll
                for (int kt = 2; kt < 4; ++kt)
                    af[mt][kt] = *(bf16x8*)&h1s[(16 * mt + l15) * 72 + 32 * (kt - 2) + 8 * qd];
            }
            f32x4 acc[4][2];
            #pragma unroll
            for (int mt = 0; mt < 4; ++mt)
                #pragma unroll
                for (int lt = 0; lt < 2; ++lt)
                    #pragma unroll
                    for (int r = 0; r < 4; ++r) acc[mt][lt][r] = b1v[lt];
            #pragma unroll
            for (int kt = 0; kt < 4; ++kt)
                #pragma unroll
                for (int mt = 0; mt < 4; ++mt)
                    #pragma unroll
                    for (int lt = 0; lt < 2; ++lt)
                        acc[mt][lt] = __builtin_amdgcn_mfma_f32_16x16x32_bf16(
                            af[mt][kt], B1[lt][kt], acc[mt][lt], 0, 0, 0);
            #pragma unroll
            for (int mt = 0; mt < 4; ++mt)
                #pragma unroll
                for (int lt = 0; lt < 2; ++lt) {
                    bf16x4 p;
                    #pragma unroll
                    for (int r = 0; r < 4; ++r) p[r] = (__bf16)acc[mt][lt][r];
                    *(bf16x4*)&Gts[(32 * w + 16 * lt + l15) * 72 + 16 * mt + 4 * qd] = p;
                }
        }
        __syncthreads();
        // Layer 1: gates
        {
            float hnew[8];
            #pragma unroll
            for (int j = 0; j < 8; ++j) {
                int d = 8 * w + j;
                float gi = (float)Gts[d * 72 + lane];
                float gf = (float)Gts[(64 + d) * 72 + lane];
                float gg = (float)Gts[(128 + d) * 72 + lane];
                float go = (float)Gts[(192 + d) * 72 + lane];
                float c = sigf(gf) * c1r[j] + sigf(gi) * tanhf_(gg);
                c1r[j] = c;
                hnew[j] = sigf(go) * tanhf_(c);
            }
            bf16x8 p;
            #pragma unroll
            for (int j = 0; j < 8; ++j) p[j] = (__bf16)hnew[j];
            *(bf16x8*)&h1s[lane * 72 + 8 * w] = p;
            if (t == TT - 1 && sseq < BN) {
                f32x4 o0, o1;
                o0[0] = hnew[0]; o0[1] = hnew[1]; o0[2] = hnew[2]; o0[3] = hnew[3];
                o1[0] = hnew[4]; o1[1] = hnew[5]; o1[2] = hnew[6]; o1[3] = hnew[7];
                *(f32x4*)&hfin[sseq * 64 + 8 * w]     = o0;
                *(f32x4*)&hfin[sseq * 64 + 8 * w + 4] = o1;
            }
        }
        __syncthreads();
    }
}

// ---------------------------------------------------------------------------
// GAT projection: hp = h @ W.T. Emits hpT (bf16, [b*64+dim][NPAD j] — the
// MFMA B-operand for gat_agg) and esT/edT (f32, [b*4+h][NPAD j]).
// Block = 4 nodes (one per wave); W staged transposed in LDS.
// ---------------------------------------------------------------------------
__global__ __launch_bounds__(256) void gat_prep(
    const float* __restrict__ hin, const float* __restrict__ W,
    const float* __restrict__ asrc, const float* __restrict__ adst,
    __bf16* __restrict__ hpT, float* __restrict__ esT, float* __restrict__ edT)
{
    __shared__ float Wt[4096];    // [k][out]
    __shared__ float av[128];     // asrc | adst
    __shared__ float hrow[256];   // [wave][k]

    int tid = threadIdx.x;
    for (int e = tid; e < 4096; e += 256) {
        Wt[e] = W[(e & 63) * 64 + (e >> 6)];
    }
    if (tid < 64) { av[tid] = asrc[tid]; av[64 + tid] = adst[tid]; }
    int wv = tid >> 6, ln = tid & 63;
    int s = blockIdx.x * 4 + wv;
    int b = s / NNODE, n = s - b * NNODE;
    hrow[wv * 64 + ln] = hin[s * 64 + ln];
    __syncthreads();

    float acc = 0.f;
    #pragma unroll
    for (int k = 0; k < 64; ++k) acc = fmaf(hrow[wv * 64 + k], Wt[k * 64 + ln], acc);
    hpT[((b << 6) + ln) * NPAD + n] = (__bf16)acc;

    float ts = acc * av[ln];
    float td = acc * av[64 + ln];
    #pragma unroll
    for (int m = 1; m <= 8; m <<= 1) {
        ts += __shfl_xor(ts, m);
        td += __shfl_xor(td, m);
    }
    if ((ln & 15) == 0) {
        int h = ln >> 4;
        esT[(b * 4 + h) * NPAD + n] = ts;
        edT[(b * 4 + h) * NPAD + n] = td;
    }
}

// ---------------------------------------------------------------------------
// GAT aggregation, flash-style MFMA. Block = 512 thr = 8 waves =
// (head 0..3) x (i-group 0..1); block covers 32 target nodes i.
// Per wave: out[16 i x 16 d] = sum_j P[16 x 128] @ hpT[128 x 16] per j-tile.
// P computed in VALU directly in A-fragment layout (i=lane&15, j=quad*8+jj):
// p = mask(i,j) ? exp(leaky(es_i + ed_j)) : 0  (no max-sub: |e| is O(1)).
// S row-sums in VALU, reduced over quad lanes; epilogue via tiny LDS.
// ---------------------------------------------------------------------------
__global__ __launch_bounds__(512) void gat_agg(
    const __bf16* __restrict__ hpT, const float* __restrict__ esT,
    const float* __restrict__ edT, const unsigned int* __restrict__ mask,
    float* __restrict__ hout)
{
    __shared__ float Ss[8][16];

    int tid  = threadIdx.x;
    int wv   = tid >> 6;
    int lane = tid & 63;
    int l15  = lane & 15;
    int qd   = lane >> 4;
    int hh   = wv & 3;          // head (wave-uniform)
    int ig   = wv >> 2;         // i-group within block
    int b    = blockIdx.x / 47;
    int it   = (blockIdx.x % 47) * 32 + ig * 16;   // wave's 16-i tile base

    const __bf16* Brow = hpT + (((b << 6) + (hh << 4) + l15) * NPAD);
    const float* edrow = edT + (b * 4 + hh) * NPAD;
    const unsigned int* mrow = mask + (it + l15) * 48;
    float esv = esT[(b * 4 + hh) * NPAD + it + l15];  // rows >=N masked anyway

    f32x4 acc = {0.f, 0.f, 0.f, 0.f};
    float S = 0.f;

    for (int jt = 0; jt < 12; ++jt) {
        uint4 mw = *(const uint4*)&mrow[jt * 4];
        #pragma unroll
        for (int kt = 0; kt < 4; ++kt) {
            int jk = jt * 128 + kt * 32 + qd * 8;
            float4 e0 = *(const float4*)&edrow[jk];
            float4 e1 = *(const float4*)&edrow[jk + 4];
            unsigned int mb = ((&mw.x)[kt] >> (qd * 8)) & 0xffu;
            float ej[8] = {e0.x, e0.y, e0.z, e0.w, e1.x, e1.y, e1.z, e1.w};
            bf16x8 A;
            #pragma unroll
            for (int jj = 0; jj < 8; ++jj) {
                float e = esv + ej[jj];
                e = fmaxf(e, 0.2f * e);               // LeakyReLU(0.2)
                float p = ((mb >> jj) & 1u) ? __expf(e) : 0.f;
                S += p;
                A[jj] = (__bf16)p;
            }
            bf16x8 B = *(const bf16x8*)&Brow[jk];
            acc = __builtin_amdgcn_mfma_f32_16x16x32_bf16(A, B, acc, 0, 0, 0);
        }
    }

    // S per i=l15: reduce over the 4 quad lanes (bits 4,5)
    S += __shfl_xor(S, 16);
    S += __shfl_xor(S, 32);
    if (qd == 0) Ss[wv][l15] = S;
    __syncthreads();

    // C/D layout: col(=d)=lane&15, row(=i)=qd*4+r
    #pragma unroll
    for (int r = 0; r < 4; ++r) {
        int i = it + qd * 4 + r;
        if (i < NNODE) {
            float rs = 1.f / Ss[wv][qd * 4 + r];
            hout[((b * NNODE + i) << 6) + (hh << 4) + l15] = fmaxf(acc[r] * rs, 0.f);
        }
    }
}

// ---------------------------------------------------------------------------
// Output head: out[b,o,n] = h2[b,n,:] . out_W[o,:] + out_b[o]
// ---------------------------------------------------------------------------
__global__ __launch_bounds__(256) void out_kernel(
    const float* __restrict__ h, const float* __restrict__ oW,
    const float* __restrict__ ob, float* __restrict__ out)
{
    int idx = blockIdx.x * 256 + threadIdx.x;
    if (idx >= NB * 3 * NNODE) return;
    int b = idx / (3 * NNODE);
    int r = idx % (3 * NNODE);
    int o = r / NNODE;
    int n = r % NNODE;
    const float* hr = h + (b * NNODE + n) * 64;
    float acc = ob[o];
    #pragma unroll
    for (int k = 0; k < 64; ++k) acc = fmaf(hr[k], oW[o * 64 + k], acc);
    out[idx] = acc;
}

// ---------------------------------------------------------------------------
extern "C" void kernel_launch(void* const* d_in, const int* in_sizes, int n_in,
                              void* d_out, int out_size, void* d_ws, size_t ws_size,
                              hipStream_t stream) {
    const float* x    = (const float*)d_in[0];
    const int*   adj  = (const int*)d_in[1];
    const float* Wih0 = (const float*)d_in[2];
    const float* Whh0 = (const float*)d_in[3];
    const float* bih0 = (const float*)d_in[4];
    const float* bhh0 = (const float*)d_in[5];
    const float* Wih1 = (const float*)d_in[6];
    const float* Whh1 = (const float*)d_in[7];
    const float* bih1 = (const float*)d_in[8];
    const float* bhh1 = (const float*)d_in[9];
    const float* g0W  = (const float*)d_in[10];
    const float* g0s  = (const float*)d_in[11];
    const float* g0d  = (const float*)d_in[12];
    const float* g1W  = (const float*)d_in[13];
    const float* g1s  = (const float*)d_in[14];
    const float* g1d  = (const float*)d_in[15];
    const float* oW   = (const float*)d_in[16];
    const float* ob   = (const float*)d_in[17];

    float* ws = (float*)d_ws;
    float*        bufh  = ws;                              // 768000 f32
    float*        esT   = ws + 768000;                     // 32*1536 = 49152
    float*        edT   = ws + 817152;                     // 49152
    __bf16*       hpT   = (__bf16*)(ws + 866304);          // 512*1536 bf16 = 393216 f32
    unsigned int* maskp = (unsigned int*)(ws + 1259520);   // 1504*48 = 72192 u32
    __bf16*       wb0   = (__bf16*)(ws + 1331712);         // 16384 bf16
    __bf16*       wb1   = (__bf16*)(ws + 1339904);         // 32768 bf16

    wconv_kernel<<<192, 256, 0, stream>>>(Whh0, Wih1, Whh1, wb0, wb1);
    mask_kernel<<<9024, 256, 0, stream>>>(adj, maskp);
    lstm_mfma<<<188, 512, 0, stream>>>(x, Wih0, bih0, bhh0, bih1, bhh1,
                                       wb0, wb1, bufh);
    gat_prep<<<3000, 256, 0, stream>>>(bufh, g0W, g0s, g0d, hpT, esT, edT);
    gat_agg<<<376, 512, 0, stream>>>(hpT, esT, edT, maskp, bufh);
    gat_prep<<<3000, 256, 0, stream>>>(bufh, g1W, g1s, g1d, hpT, esT, edT);
    gat_agg<<<376, 512, 0, stream>>>(hpT, esT, edT, maskp, bufh);
    out_kernel<<<141, 256, 0, stream>>>(bufh, oW, ob, (float*)d_out);
}

// Round 6
// 328.709 us; speedup vs baseline: 7.4669x; 1.0127x over previous
//
#include <hip/hip_runtime.h>
#include <hip/hip_bf16.h>

// GATPredictor: x(8,12,1500) f32 -> 2-layer LSTM(hid64) per (b,n) sequence ->
// 2x GAT(4 heads x 16) over N=1500 graph -> linear head (3) -> (B,3,N) f32.
// LSTM: merged-phase MFMA (L0(t+1)+L1(t) in one phase, 2 barriers/step),
// gates kept in f32 regs + wave shuffles (no LDS round-trip).
// GAT aggregation: flash-style MFMA (round 5, verified).

#define BN 12000
#define NNODE 1500
#define NB 8
#define TT 12
#define NPAD 1536   // padded j extent for hpT/esT/edT rows
#define SEQB 48     // sequences per LSTM block (250 blocks exactly)

typedef __bf16 bf16x8 __attribute__((ext_vector_type(8)));
typedef __bf16 bf16x4 __attribute__((ext_vector_type(4)));
typedef float  f32x4  __attribute__((ext_vector_type(4)));

__device__ __forceinline__ float sigf(float v) { return 1.f / (1.f + __expf(-v)); }

__device__ __forceinline__ float tanhf_(float v) {
    float a = fabsf(v);
    float e = __expf(-2.f * a);
    float r = (1.f - e) / (1.f + e);
    return v < 0.f ? -r : r;
}

// ---------------------------------------------------------------------------
// Convert LSTM matmul weights to bf16 in ws.
// wb0[g*64+k]  = Whh0[g][k]; wb1[g*128+k] = k<64 ? Wih1[g][k] : Whh1[g][k-64]
// ---------------------------------------------------------------------------
__global__ __launch_bounds__(256) void wconv_kernel(
    const float* __restrict__ Whh0, const float* __restrict__ Wih1,
    const float* __restrict__ Whh1,
    __bf16* __restrict__ wb0, __bf16* __restrict__ wb1)
{
    int i = blockIdx.x * 256 + threadIdx.x;
    if (i < 16384) {
        wb0[i] = (__bf16)Whh0[i];
    } else if (i < 49152) {
        int j = i - 16384;
        int g = j >> 7, k = j & 127;
        wb1[j] = (__bf16)(k < 64 ? Wih1[(g << 6) + k] : Whh1[(g << 6) + k - 64]);
    }
}

// ---------------------------------------------------------------------------
// Adjacency bitmask: mask[i][w] bits j in [w*32, w*32+32). 1504 x 48 words.
// ---------------------------------------------------------------------------
__global__ __launch_bounds__(256) void mask_kernel(
    const int* __restrict__ adj, unsigned int* __restrict__ mask)
{
    int idx  = blockIdx.x * 4 + (threadIdx.x >> 6);
    int lane = threadIdx.x & 63;
    int i  = idx / 24;
    int ch = idx - i * 24;
    if (i >= 1504) return;
    int j = ch * 64 + lane;
    int a = (i < NNODE && j < NNODE) ? adj[i * NNODE + j] : 0;
    unsigned long long m = __ballot(a > 0);
    if (lane == 0) *(unsigned long long*)&mask[i * 48 + ch * 2] = m;
}

// ---------------------------------------------------------------------------
// Merged-phase MFMA 2-layer LSTM. Block = 48 seqs, 512 thr (8 waves).
// Wave w owns all 4 gates of dims 8w..8w+7: tileA columns = gate i (l15<8) /
// f (l15>=8) of dim 8w+(l15&7); tileB = g / o. Per step ONE MFMA phase
// computes G1(t) (K=128: [h0(t);h1(t-1)]) and G0(t+1) (Whh0@h0(t), x+bias in
// acc init), then ONE gate phase: partner gates fetched via shfl_xor(8),
// c-state in regs, h written to LDS (bf16, stride-72 rows). 2 barriers/step.
// ---------------------------------------------------------------------------
__global__ __launch_bounds__(512, 1) void lstm_mfma(
    const float* __restrict__ x,
    const float* __restrict__ Wih0,
    const float* __restrict__ bih0, const float* __restrict__ bhh0,
    const float* __restrict__ bih1, const float* __restrict__ bhh1,
    const __bf16* __restrict__ wb0, const __bf16* __restrict__ wb1,
    float* __restrict__ hfin)
{
    __shared__ __align__(16) __bf16 h0s[SEQB * 72];   // 6.75 KB
    __shared__ __align__(16) __bf16 h1s[SEQB * 72];   // 6.75 KB
    __shared__ __align__(16) float  xls[TT * SEQB];   // 2.25 KB

    int tid  = threadIdx.x;
    int w    = __builtin_amdgcn_readfirstlane(tid >> 6);
    int lane = tid & 63;
    int l15  = lane & 15;
    int qd   = lane >> 4;
    bool lo  = l15 < 8;          // low half of the 16-column tile
    int dloc = l15 & 7;
    int d    = 8 * w + dloc;     // owned hidden dim

    // zero h1 state (cols 0..63 used; pad junk never read)
    for (int e = tid; e < (SEQB * 72) / 2; e += 512) ((unsigned int*)h1s)[e] = 0u;
    // stage x tile: xls[t][m], m = 0..47 (always valid: 250*48 == 12000)
    for (int e = tid; e < TT * SEQB; e += 512) {
        int t = e / SEQB, m = e - t * SEQB;
        int s = blockIdx.x * SEQB + m;
        int bb = s / NNODE, nn = s - bb * NNODE;
        xls[e] = x[bb * (TT * NNODE) + t * NNODE + nn];
    }

    // B-fragment columns: gA = i|f of dim d, gB = g|o of dim d
    int gA = (lo ? 0 : 64) + d;
    int gB = (lo ? 128 : 192) + d;
    bf16x8 B0A[2], B0B[2], B1A[4], B1B[4];
    #pragma unroll
    for (int kt = 0; kt < 2; ++kt) {
        B0A[kt] = *(const bf16x8*)&wb0[gA * 64 + 32 * kt + 8 * qd];
        B0B[kt] = *(const bf16x8*)&wb0[gB * 64 + 32 * kt + 8 * qd];
    }
    #pragma unroll
    for (int kt = 0; kt < 4; ++kt) {
        B1A[kt] = *(const bf16x8*)&wb1[gA * 128 + 32 * kt + 8 * qd];
        B1B[kt] = *(const bf16x8*)&wb1[gB * 128 + 32 * kt + 8 * qd];
    }
    float b0A = bih0[gA] + bhh0[gA], b0B = bih0[gB] + bhh0[gB];
    float b1A = bih1[gA] + bhh1[gA], b1B = bih1[gB] + bhh1[gB];
    float w0A = Wih0[gA], w0B = Wih0[gB];

    // per-thread gate constants for the prologue (dim d, all 4 gates)
    float pwi = Wih0[d],       pbi = bih0[d]       + bhh0[d];
    float pwf = Wih0[64 + d],  pbf = bih0[64 + d]  + bhh0[64 + d];
    float pwg = Wih0[128 + d], pbg = bih0[128 + d] + bhh0[128 + d];
    float pwo = Wih0[192 + d], pbo = bih0[192 + d] + bhh0[192 + d];

    float c0[3][2], c1[3][2];
    #pragma unroll
    for (int mt = 0; mt < 3; ++mt) { c0[mt][0] = c0[mt][1] = c1[mt][0] = c1[mt][1] = 0.f; }

    __syncthreads();   // xls ready

    // ---- prologue: h0(0) = gates(Wih0*x0 + b), h_prev = 0 (pure VALU) ----
    #pragma unroll
    for (int mt = 0; mt < 3; ++mt)
        #pragma unroll
        for (int rl = 0; rl < 2; ++rl) {
            int rr = lo ? rl : 2 + rl;
            int m = 16 * mt + 4 * qd + rr;
            float xv = xls[m];
            float gi = fmaf(pwi, xv, pbi), gf = fmaf(pwf, xv, pbf);
            float gg = fmaf(pwg, xv, pbg), go = fmaf(pwo, xv, pbo);
            (void)gf;
            float c = sigf(gi) * tanhf_(gg);
            c0[mt][rl] = c;
            h0s[m * 72 + d] = (__bf16)(sigf(go) * tanhf_(c));
        }
    __syncthreads();

    for (int t = 0; t < TT; ++t) {
        bool last = (t == TT - 1);
        // ===== phase 1: all MFMAs (G1(t), and G0(t+1) unless last) =====
        bf16x8 a0[3][2], a1[3][2];
        #pragma unroll
        for (int mt = 0; mt < 3; ++mt)
            #pragma unroll
            for (int kt = 0; kt < 2; ++kt) {
                a0[mt][kt] = *(bf16x8*)&h0s[(16 * mt + l15) * 72 + 32 * kt + 8 * qd];
                a1[mt][kt] = *(bf16x8*)&h1s[(16 * mt + l15) * 72 + 32 * kt + 8 * qd];
            }
        f32x4 AA1[3], AB1[3], AA0[3], AB0[3];
        #pragma unroll
        for (int mt = 0; mt < 3; ++mt) {
            #pragma unroll
            for (int r = 0; r < 4; ++r) { AA1[mt][r] = b1A; AB1[mt][r] = b1B; }
            if (!last) {
                f32x4 xv = *(f32x4*)&xls[(t + 1) * SEQB + 16 * mt + 4 * qd];
                #pragma unroll
                for (int r = 0; r < 4; ++r) {
                    AA0[mt][r] = fmaf(w0A, xv[r], b0A);
                    AB0[mt][r] = fmaf(w0B, xv[r], b0B);
                }
            }
        }
        #pragma unroll
        for (int mt = 0; mt < 3; ++mt) {
            #pragma unroll
            for (int kt = 0; kt < 2; ++kt) {
                AA1[mt] = __builtin_amdgcn_mfma_f32_16x16x32_bf16(a0[mt][kt], B1A[kt], AA1[mt], 0, 0, 0);
                AB1[mt] = __builtin_amdgcn_mfma_f32_16x16x32_bf16(a0[mt][kt], B1B[kt], AB1[mt], 0, 0, 0);
                AA1[mt] = __builtin_amdgcn_mfma_f32_16x16x32_bf16(a1[mt][kt], B1A[kt + 2], AA1[mt], 0, 0, 0);
                AB1[mt] = __builtin_amdgcn_mfma_f32_16x16x32_bf16(a1[mt][kt], B1B[kt + 2], AB1[mt], 0, 0, 0);
            }
            if (!last) {
                #pragma unroll
                for (int kt = 0; kt < 2; ++kt) {
                    AA0[mt] = __builtin_amdgcn_mfma_f32_16x16x32_bf16(a0[mt][kt], B0A[kt], AA0[mt], 0, 0, 0);
                    AB0[mt] = __builtin_amdgcn_mfma_f32_16x16x32_bf16(a0[mt][kt], B0B[kt], AB0[mt], 0, 0, 0);
                }
            }
        }
        __syncthreads();   // all h reads of this step done

        // ===== phase 2: gates (partner gates via shfl_xor 8) =====
        #pragma unroll
        for (int mt = 0; mt < 3; ++mt) {
            // ---- layer 1 -> h1(t) ----
            {
                float shA0 = __shfl_xor(lo ? AA1[mt][2] : AA1[mt][0], 8);
                float shA1 = __shfl_xor(lo ? AA1[mt][3] : AA1[mt][1], 8);
                float shB0 = __shfl_xor(lo ? AB1[mt][2] : AB1[mt][0], 8);
                float shB1 = __shfl_xor(lo ? AB1[mt][3] : AB1[mt][1], 8);
                #pragma unroll
                for (int rl = 0; rl < 2; ++rl) {
                    int rr = lo ? rl : 2 + rl;
                    float ownA = AA1[mt][rr], ownB = AB1[mt][rr];
                    float shA = rl ? shA1 : shA0, shB = rl ? shB1 : shB0;
                    float gi = lo ? ownA : shA;
                    float gf = lo ? shA : ownA;
                    float gg = lo ? ownB : shB;
                    float go = lo ? shB : ownB;
                    float c = sigf(gf) * c1[mt][rl] + sigf(gi) * tanhf_(gg);
                    c1[mt][rl] = c;
                    float hv = sigf(go) * tanhf_(c);
                    int m = 16 * mt + 4 * qd + rr;
                    if (!last) h1s[m * 72 + d] = (__bf16)hv;
                    else       hfin[(blockIdx.x * SEQB + m) * 64 + d] = hv;
                }
            }
            // ---- layer 0 -> h0(t+1) ----
            if (!last) {
                float shA0 = __shfl_xor(lo ? AA0[mt][2] : AA0[mt][0], 8);
                float shA1 = __shfl_xor(lo ? AA0[mt][3] : AA0[mt][1], 8);
                float shB0 = __shfl_xor(lo ? AB0[mt][2] : AB0[mt][0], 8);
                float shB1 = __shfl_xor(lo ? AB0[mt][3] : AB0[mt][1], 8);
                #pragma unroll
                for (int rl = 0; rl < 2; ++rl) {
                    int rr = lo ? rl : 2 + rl;
                    float ownA = AA0[mt][rr], ownB = AB0[mt][rr];
                    float shA = rl ? shA1 : shA0, shB = rl ? shB1 : shB0;
                    float gi = lo ? ownA : shA;
                    float gf = lo ? shA : ownA;
                    float gg = lo ? ownB : shB;
                    float go = lo ? shB : ownB;
                    float c = sigf(gf) * c0[mt][rl] + sigf(gi) * tanhf_(gg);
                    c0[mt][rl] = c;
                    int m = 16 * mt + 4 * qd + rr;
                    h0s[m * 72 + d] = (__bf16)(sigf(go) * tanhf_(c));
                }
            }
        }
        __syncthreads();   // new h visible before next phase 1
    }
}

// ---------------------------------------------------------------------------
// GAT projection: hp = h @ W.T. Emits hpT (bf16, [b*64+dim][NPAD j]) and
// esT/edT (f32, [b*4+h][NPAD j]). Block = 4 nodes (one per wave).
// ---------------------------------------------------------------------------
__global__ __launch_bounds__(256) void gat_prep(
    const float* __restrict__ hin, const float* __restrict__ W,
    const float* __restrict__ asrc, const float* __restrict__ adst,
    __bf16* __restrict__ hpT, float* __restrict__ esT, float* __restrict__ edT)
{
    __shared__ float Wt[4096];    // [k][out]
    __shared__ float av[128];     // asrc | adst
    __shared__ float hrow[256];   // [wave][k]

    int tid = threadIdx.x;
    for (int e = tid; e < 4096; e += 256) {
        Wt[e] = W[(e & 63) * 64 + (e >> 6)];
    }
    if (tid < 64) { av[tid] = asrc[tid]; av[64 + tid] = adst[tid]; }
    int wv = tid >> 6, ln = tid & 63;
    int s = blockIdx.x * 4 + wv;
    int b = s / NNODE, n = s - b * NNODE;
    hrow[wv * 64 + ln] = hin[s * 64 + ln];
    __syncthreads();

    float acc = 0.f;
    #pragma unroll
    for (int k = 0; k < 64; ++k) acc = fmaf(hrow[wv * 64 + k], Wt[k * 64 + ln], acc);
    hpT[((b << 6) + ln) * NPAD + n] = (__bf16)acc;

    float ts = acc * av[ln];
    float td = acc * av[64 + ln];
    #pragma unroll
    for (int m = 1; m <= 8; m <<= 1) {
        ts += __shfl_xor(ts, m);
        td += __shfl_xor(td, m);
    }
    if ((ln & 15) == 0) {
        int h = ln >> 4;
        esT[(b * 4 + h) * NPAD + n] = ts;
        edT[(b * 4 + h) * NPAD + n] = td;
    }
}

// ---------------------------------------------------------------------------
// GAT aggregation, flash-style MFMA (round 5, verified).
// ---------------------------------------------------------------------------
__global__ __launch_bounds__(512) void gat_agg(
    const __bf16* __restrict__ hpT, const float* __restrict__ esT,
    const float* __restrict__ edT, const unsigned int* __restrict__ mask,
    float* __restrict__ hout)
{
    __shared__ float Ss[8][16];

    int tid  = threadIdx.x;
    int wv   = tid >> 6;
    int lane = tid & 63;
    int l15  = lane & 15;
    int qd   = lane >> 4;
    int hh   = wv & 3;
    int ig   = wv >> 2;
    int b    = blockIdx.x / 47;
    int it   = (blockIdx.x % 47) * 32 + ig * 16;

    const __bf16* Brow = hpT + (((b << 6) + (hh << 4) + l15) * NPAD);
    const float* edrow = edT + (b * 4 + hh) * NPAD;
    const unsigned int* mrow = mask + (it + l15) * 48;
    float esv = esT[(b * 4 + hh) * NPAD + it + l15];

    f32x4 acc = {0.f, 0.f, 0.f, 0.f};
    float S = 0.f;

    for (int jt = 0; jt < 12; ++jt) {
        uint4 mw = *(const uint4*)&mrow[jt * 4];
        #pragma unroll
        for (int kt = 0; kt < 4; ++kt) {
            int jk = jt * 128 + kt * 32 + qd * 8;
            float4 e0 = *(const float4*)&edrow[jk];
            float4 e1 = *(const float4*)&edrow[jk + 4];
            unsigned int mb = ((&mw.x)[kt] >> (qd * 8)) & 0xffu;
            float ej[8] = {e0.x, e0.y, e0.z, e0.w, e1.x, e1.y, e1.z, e1.w};
            bf16x8 A;
            #pragma unroll
            for (int jj = 0; jj < 8; ++jj) {
                float e = esv + ej[jj];
                e = fmaxf(e, 0.2f * e);
                float p = ((mb >> jj) & 1u) ? __expf(e) : 0.f;
                S += p;
                A[jj] = (__bf16)p;
            }
            bf16x8 B = *(const bf16x8*)&Brow[jk];
            acc = __builtin_amdgcn_mfma_f32_16x16x32_bf16(A, B, acc, 0, 0, 0);
        }
    }

    S += __shfl_xor(S, 16);
    S += __shfl_xor(S, 32);
    if (qd == 0) Ss[wv][l15] = S;
    __syncthreads();

    #pragma unroll
    for (int r = 0; r < 4; ++r) {
        int i = it + qd * 4 + r;
        if (i < NNODE) {
            float rs = 1.f / Ss[wv][qd * 4 + r];
            hout[((b * NNODE + i) << 6) + (hh << 4) + l15] = fmaxf(acc[r] * rs, 0.f);
        }
    }
}

// ---------------------------------------------------------------------------
// Output head, coalesced: 4 lanes per node (k-split 16 each), shuffle-reduce.
// out[b,o,n] = h2[b,n,:] . out_W[o,:] + out_b[o]
// ---------------------------------------------------------------------------
__global__ __launch_bounds__(256) void out_kernel(
    const float* __restrict__ h, const float* __restrict__ oW,
    const float* __restrict__ ob, float* __restrict__ out)
{
    __shared__ float oWs[192];
    __shared__ float obs[3];
    int tid = threadIdx.x;
    if (tid < 192) oWs[tid] = oW[tid];
    if (tid < 3)   obs[tid] = ob[tid];
    __syncthreads();

    int g = blockIdx.x * 256 + tid;
    int node = g >> 2;
    int ks   = g & 3;
    if (node >= BN) return;    // whole trailing waves exit together

    float hv[16];
    const float* hr = h + node * 64 + ks * 16;
    *(float4*)&hv[0]  = *(const float4*)&hr[0];
    *(float4*)&hv[4]  = *(const float4*)&hr[4];
    *(float4*)&hv[8]  = *(const float4*)&hr[8];
    *(float4*)&hv[12] = *(const float4*)&hr[12];

    float a0 = 0.f, a1 = 0.f, a2 = 0.f;
    #pragma unroll
    for (int kk = 0; kk < 16; ++kk) {
        int k = ks * 16 + kk;
        float xv = hv[kk];
        a0 = fmaf(xv, oWs[k], a0);
        a1 = fmaf(xv, oWs[64 + k], a1);
        a2 = fmaf(xv, oWs[128 + k], a2);
    }
    a0 += __shfl_xor(a0, 1); a0 += __shfl_xor(a0, 2);
    a1 += __shfl_xor(a1, 1); a1 += __shfl_xor(a1, 2);
    a2 += __shfl_xor(a2, 1); a2 += __shfl_xor(a2, 2);
    if (ks == 0) {
        int b = node / NNODE, n = node - b * NNODE;
        float* o = out + (long)b * 3 * NNODE + n;
        o[0]         = a0 + obs[0];
        o[NNODE]     = a1 + obs[1];
        o[2 * NNODE] = a2 + obs[2];
    }
}

// ---------------------------------------------------------------------------
extern "C" void kernel_launch(void* const* d_in, const int* in_sizes, int n_in,
                              void* d_out, int out_size, void* d_ws, size_t ws_size,
                              hipStream_t stream) {
    const float* x    = (const float*)d_in[0];
    const int*   adj  = (const int*)d_in[1];
    const float* Wih0 = (const float*)d_in[2];
    const float* Whh0 = (const float*)d_in[3];
    const float* bih0 = (const float*)d_in[4];
    const float* bhh0 = (const float*)d_in[5];
    const float* Wih1 = (const float*)d_in[6];
    const float* Whh1 = (const float*)d_in[7];
    const float* bih1 = (const float*)d_in[8];
    const float* bhh1 = (const float*)d_in[9];
    const float* g0W  = (const float*)d_in[10];
    const float* g0s  = (const float*)d_in[11];
    const float* g0d  = (const float*)d_in[12];
    const float* g1W  = (const float*)d_in[13];
    const float* g1s  = (const float*)d_in[14];
    const float* g1d  = (const float*)d_in[15];
    const float* oW   = (const float*)d_in[16];
    const float* ob   = (const float*)d_in[17];

    float* ws = (float*)d_ws;
    float*        bufh  = ws;                              // 768000 f32
    float*        esT   = ws + 768000;                     // 49152
    float*        edT   = ws + 817152;                     // 49152
    __bf16*       hpT   = (__bf16*)(ws + 866304);          // 512*1536 bf16
    unsigned int* maskp = (unsigned int*)(ws + 1259520);   // 72192 u32
    __bf16*       wb0   = (__bf16*)(ws + 1331712);         // 16384 bf16
    __bf16*       wb1   = (__bf16*)(ws + 1339904);         // 32768 bf16

    wconv_kernel<<<192, 256, 0, stream>>>(Whh0, Wih1, Whh1, wb0, wb1);
    lstm_mfma<<<250, 512, 0, stream>>>(x, Wih0, bih0, bhh0, bih1, bhh1,
                                       wb0, wb1, bufh);
    mask_kernel<<<9024, 256, 0, stream>>>(adj, maskp);
    gat_prep<<<3000, 256, 0, stream>>>(bufh, g0W, g0s, g0d, hpT, esT, edT);
    gat_agg<<<376, 512, 0, stream>>>(hpT, esT, edT, maskp, bufh);
    gat_prep<<<3000, 256, 0, stream>>>(bufh, g1W, g1s, g1d, hpT, esT, edT);
    gat_agg<<<376, 512, 0, stream>>>(hpT, esT, edT, maskp, bufh);
    out_kernel<<<188, 256, 0, stream>>>(bufh, oW, ob, (float*)d_out);
}

// Round 7
// 268.608 us; speedup vs baseline: 9.1376x; 1.2238x over previous
//
#include <hip/hip_runtime.h>
#include <hip/hip_bf16.h>

// GATPredictor: x(8,12,1500) f32 -> 2-layer LSTM(hid64) per (b,n) sequence ->
// 2x GAT(4 heads x 16) over N=1500 graph -> linear head (3) -> (B,3,N) f32.
// LSTM: merged-phase MFMA (2 barriers/step) + fast rcp-based activations.
// GAT aggregation: flash-style MFMA. gat_prep: 16 nodes/block, shfl-broadcast.

#define BN 12000
#define NNODE 1500
#define NB 8
#define TT 12
#define NPAD 1536   // padded j extent for hpT/esT/edT rows
#define SEQB 48     // sequences per LSTM block (250 blocks exactly)

typedef __bf16 bf16x8 __attribute__((ext_vector_type(8)));
typedef __bf16 bf16x4 __attribute__((ext_vector_type(4)));
typedef float  f32x4  __attribute__((ext_vector_type(4)));

// fast activations: v_rcp_f32 (~1 ulp) instead of IEEE division (~10 instr).
// exp overflow -> inf -> rcp -> 0 gives the correct saturation limit.
__device__ __forceinline__ float rcpf(float v) { return __builtin_amdgcn_rcpf(v); }
__device__ __forceinline__ float sigf(float v) { return rcpf(1.f + __expf(-v)); }
__device__ __forceinline__ float tanhf_(float v) {
    return fmaf(2.f, rcpf(1.f + __expf(-2.f * v)), -1.f);
}

// ---------------------------------------------------------------------------
// Convert LSTM matmul weights to bf16 in ws.
// wb0[g*64+k]  = Whh0[g][k]; wb1[g*128+k] = k<64 ? Wih1[g][k] : Whh1[g][k-64]
// ---------------------------------------------------------------------------
__global__ __launch_bounds__(256) void wconv_kernel(
    const float* __restrict__ Whh0, const float* __restrict__ Wih1,
    const float* __restrict__ Whh1,
    __bf16* __restrict__ wb0, __bf16* __restrict__ wb1)
{
    int i = blockIdx.x * 256 + threadIdx.x;
    if (i < 16384) {
        wb0[i] = (__bf16)Whh0[i];
    } else if (i < 49152) {
        int j = i - 16384;
        int g = j >> 7, k = j & 127;
        wb1[j] = (__bf16)(k < 64 ? Wih1[(g << 6) + k] : Whh1[(g << 6) + k - 64]);
    }
}

// ---------------------------------------------------------------------------
// Adjacency bitmask: mask[i][w] bits j in [w*32, w*32+32). 1504 x 48 words.
// ---------------------------------------------------------------------------
__global__ __launch_bounds__(256) void mask_kernel(
    const int* __restrict__ adj, unsigned int* __restrict__ mask)
{
    int idx  = blockIdx.x * 4 + (threadIdx.x >> 6);
    int lane = threadIdx.x & 63;
    int i  = idx / 24;
    int ch = idx - i * 24;
    if (i >= 1504) return;
    int j = ch * 64 + lane;
    int a = (i < NNODE && j < NNODE) ? adj[i * NNODE + j] : 0;
    unsigned long long m = __ballot(a > 0);
    if (lane == 0) *(unsigned long long*)&mask[i * 48 + ch * 2] = m;
}

// ---------------------------------------------------------------------------
// Merged-phase MFMA 2-layer LSTM (round-6 structure, verified) + fast gates.
// Block = 48 seqs, 512 thr (8 waves). 2 barriers/step.
// ---------------------------------------------------------------------------
__global__ __launch_bounds__(512, 1) void lstm_mfma(
    const float* __restrict__ x,
    const float* __restrict__ Wih0,
    const float* __restrict__ bih0, const float* __restrict__ bhh0,
    const float* __restrict__ bih1, const float* __restrict__ bhh1,
    const __bf16* __restrict__ wb0, const __bf16* __restrict__ wb1,
    float* __restrict__ hfin)
{
    __shared__ __align__(16) __bf16 h0s[SEQB * 72];   // 6.75 KB
    __shared__ __align__(16) __bf16 h1s[SEQB * 72];   // 6.75 KB
    __shared__ __align__(16) float  xls[TT * SEQB];   // 2.25 KB

    int tid  = threadIdx.x;
    int w    = __builtin_amdgcn_readfirstlane(tid >> 6);
    int lane = tid & 63;
    int l15  = lane & 15;
    int qd   = lane >> 4;
    bool lo  = l15 < 8;          // low half of the 16-column tile
    int dloc = l15 & 7;
    int d    = 8 * w + dloc;     // owned hidden dim

    for (int e = tid; e < (SEQB * 72) / 2; e += 512) ((unsigned int*)h1s)[e] = 0u;
    for (int e = tid; e < TT * SEQB; e += 512) {
        int t = e / SEQB, m = e - t * SEQB;
        int s = blockIdx.x * SEQB + m;
        int bb = s / NNODE, nn = s - bb * NNODE;
        xls[e] = x[bb * (TT * NNODE) + t * NNODE + nn];
    }

    // B-fragment columns: gA = i|f of dim d, gB = g|o of dim d
    int gA = (lo ? 0 : 64) + d;
    int gB = (lo ? 128 : 192) + d;
    bf16x8 B0A[2], B0B[2], B1A[4], B1B[4];
    #pragma unroll
    for (int kt = 0; kt < 2; ++kt) {
        B0A[kt] = *(const bf16x8*)&wb0[gA * 64 + 32 * kt + 8 * qd];
        B0B[kt] = *(const bf16x8*)&wb0[gB * 64 + 32 * kt + 8 * qd];
    }
    #pragma unroll
    for (int kt = 0; kt < 4; ++kt) {
        B1A[kt] = *(const bf16x8*)&wb1[gA * 128 + 32 * kt + 8 * qd];
        B1B[kt] = *(const bf16x8*)&wb1[gB * 128 + 32 * kt + 8 * qd];
    }
    float b0A = bih0[gA] + bhh0[gA], b0B = bih0[gB] + bhh0[gB];
    float b1A = bih1[gA] + bhh1[gA], b1B = bih1[gB] + bhh1[gB];
    float w0A = Wih0[gA], w0B = Wih0[gB];

    float pwi = Wih0[d],       pbi = bih0[d]       + bhh0[d];
    float pwg = Wih0[128 + d], pbg = bih0[128 + d] + bhh0[128 + d];
    float pwo = Wih0[192 + d], pbo = bih0[192 + d] + bhh0[192 + d];

    float c0[3][2], c1[3][2];
    #pragma unroll
    for (int mt = 0; mt < 3; ++mt) { c0[mt][0] = c0[mt][1] = c1[mt][0] = c1[mt][1] = 0.f; }

    __syncthreads();   // xls ready

    // ---- prologue: h0(0) = gates(Wih0*x0 + b), h_prev = 0 (pure VALU) ----
    #pragma unroll
    for (int mt = 0; mt < 3; ++mt)
        #pragma unroll
        for (int rl = 0; rl < 2; ++rl) {
            int rr = lo ? rl : 2 + rl;
            int m = 16 * mt + 4 * qd + rr;
            float xv = xls[m];
            float gi = fmaf(pwi, xv, pbi);
            float gg = fmaf(pwg, xv, pbg);
            float go = fmaf(pwo, xv, pbo);
            float c = sigf(gi) * tanhf_(gg);
            c0[mt][rl] = c;
            h0s[m * 72 + d] = (__bf16)(sigf(go) * tanhf_(c));
        }
    __syncthreads();

    for (int t = 0; t < TT; ++t) {
        bool last = (t == TT - 1);
        // ===== phase 1: all MFMAs (G1(t), and G0(t+1) unless last) =====
        bf16x8 a0[3][2], a1[3][2];
        #pragma unroll
        for (int mt = 0; mt < 3; ++mt)
            #pragma unroll
            for (int kt = 0; kt < 2; ++kt) {
                a0[mt][kt] = *(bf16x8*)&h0s[(16 * mt + l15) * 72 + 32 * kt + 8 * qd];
                a1[mt][kt] = *(bf16x8*)&h1s[(16 * mt + l15) * 72 + 32 * kt + 8 * qd];
            }
        f32x4 AA1[3], AB1[3], AA0[3], AB0[3];
        #pragma unroll
        for (int mt = 0; mt < 3; ++mt) {
            #pragma unroll
            for (int r = 0; r < 4; ++r) { AA1[mt][r] = b1A; AB1[mt][r] = b1B; }
            if (!last) {
                f32x4 xv = *(f32x4*)&xls[(t + 1) * SEQB + 16 * mt + 4 * qd];
                #pragma unroll
                for (int r = 0; r < 4; ++r) {
                    AA0[mt][r] = fmaf(w0A, xv[r], b0A);
                    AB0[mt][r] = fmaf(w0B, xv[r], b0B);
                }
            }
        }
        #pragma unroll
        for (int mt = 0; mt < 3; ++mt) {
            #pragma unroll
            for (int kt = 0; kt < 2; ++kt) {
                AA1[mt] = __builtin_amdgcn_mfma_f32_16x16x32_bf16(a0[mt][kt], B1A[kt], AA1[mt], 0, 0, 0);
                AB1[mt] = __builtin_amdgcn_mfma_f32_16x16x32_bf16(a0[mt][kt], B1B[kt], AB1[mt], 0, 0, 0);
                AA1[mt] = __builtin_amdgcn_mfma_f32_16x16x32_bf16(a1[mt][kt], B1A[kt + 2], AA1[mt], 0, 0, 0);
                AB1[mt] = __builtin_amdgcn_mfma_f32_16x16x32_bf16(a1[mt][kt], B1B[kt + 2], AB1[mt], 0, 0, 0);
            }
            if (!last) {
                #pragma unroll
                for (int kt = 0; kt < 2; ++kt) {
                    AA0[mt] = __builtin_amdgcn_mfma_f32_16x16x32_bf16(a0[mt][kt], B0A[kt], AA0[mt], 0, 0, 0);
                    AB0[mt] = __builtin_amdgcn_mfma_f32_16x16x32_bf16(a0[mt][kt], B0B[kt], AB0[mt], 0, 0, 0);
                }
            }
        }
        __syncthreads();   // all h reads of this step done

        // ===== phase 2: gates (partner gates via shfl_xor 8) =====
        #pragma unroll
        for (int mt = 0; mt < 3; ++mt) {
            // ---- layer 1 -> h1(t) ----
            {
                float shA0 = __shfl_xor(lo ? AA1[mt][2] : AA1[mt][0], 8);
                float shA1 = __shfl_xor(lo ? AA1[mt][3] : AA1[mt][1], 8);
                float shB0 = __shfl_xor(lo ? AB1[mt][2] : AB1[mt][0], 8);
                float shB1 = __shfl_xor(lo ? AB1[mt][3] : AB1[mt][1], 8);
                #pragma unroll
                for (int rl = 0; rl < 2; ++rl) {
                    int rr = lo ? rl : 2 + rl;
                    float ownA = AA1[mt][rr], ownB = AB1[mt][rr];
                    float shA = rl ? shA1 : shA0, shB = rl ? shB1 : shB0;
                    float gi = lo ? ownA : shA;
                    float gf = lo ? shA : ownA;
                    float gg = lo ? ownB : shB;
                    float go = lo ? shB : ownB;
                    float c = sigf(gf) * c1[mt][rl] + sigf(gi) * tanhf_(gg);
                    c1[mt][rl] = c;
                    float hv = sigf(go) * tanhf_(c);
                    int m = 16 * mt + 4 * qd + rr;
                    if (!last) h1s[m * 72 + d] = (__bf16)hv;
                    else       hfin[(blockIdx.x * SEQB + m) * 64 + d] = hv;
                }
            }
            // ---- layer 0 -> h0(t+1) ----
            if (!last) {
                float shA0 = __shfl_xor(lo ? AA0[mt][2] : AA0[mt][0], 8);
                float shA1 = __shfl_xor(lo ? AA0[mt][3] : AA0[mt][1], 8);
                float shB0 = __shfl_xor(lo ? AB0[mt][2] : AB0[mt][0], 8);
                float shB1 = __shfl_xor(lo ? AB0[mt][3] : AB0[mt][1], 8);
                #pragma unroll
                for (int rl = 0; rl < 2; ++rl) {
                    int rr = lo ? rl : 2 + rl;
                    float ownA = AA0[mt][rr], ownB = AB0[mt][rr];
                    float shA = rl ? shA1 : shA0, shB = rl ? shB1 : shB0;
                    float gi = lo ? ownA : shA;
                    float gf = lo ? shA : ownA;
                    float gg = lo ? ownB : shB;
                    float go = lo ? shB : ownB;
                    float c = sigf(gf) * c0[mt][rl] + sigf(gi) * tanhf_(gg);
                    c0[mt][rl] = c;
                    int m = 16 * mt + 4 * qd + rr;
                    h0s[m * 72 + d] = (__bf16)(sigf(go) * tanhf_(c));
                }
            }
        }
        __syncthreads();   // new h visible before next phase 1
    }
}

// ---------------------------------------------------------------------------
// GAT projection: hp = h @ W.T. Emits hpT (bf16, [b*64+dim][NPAD j]) and
// esT/edT (f32, [b*4+h][NPAD j]). Block = 16 nodes (4 iters x 4 waves);
// W staged once per block; h row broadcast via __shfl (no LDS round-trip).
// ---------------------------------------------------------------------------
__global__ __launch_bounds__(256) void gat_prep(
    const float* __restrict__ hin, const float* __restrict__ W,
    const float* __restrict__ asrc, const float* __restrict__ adst,
    __bf16* __restrict__ hpT, float* __restrict__ esT, float* __restrict__ edT)
{
    __shared__ float Wt[4096];    // [k][out]
    __shared__ float av[128];     // asrc | adst

    int tid = threadIdx.x;
    for (int e = tid; e < 4096; e += 256) {
        Wt[e] = W[(e & 63) * 64 + (e >> 6)];
    }
    if (tid < 64)       av[tid] = asrc[tid];
    else if (tid < 128) av[tid] = adst[tid - 64];
    int wv = tid >> 6, ln = tid & 63;
    __syncthreads();

    #pragma unroll
    for (int r = 0; r < 4; ++r) {
        int s = blockIdx.x * 16 + r * 4 + wv;
        int b = s / NNODE, n = s - b * NNODE;
        float hval = hin[s * 64 + ln];

        float acc = 0.f;
        #pragma unroll
        for (int k = 0; k < 64; ++k)
            acc = fmaf(__shfl(hval, k), Wt[k * 64 + ln], acc);
        hpT[((b << 6) + ln) * NPAD + n] = (__bf16)acc;

        float ts = acc * av[ln];
        float td = acc * av[64 + ln];
        #pragma unroll
        for (int m = 1; m <= 8; m <<= 1) {
            ts += __shfl_xor(ts, m);
            td += __shfl_xor(td, m);
        }
        if ((ln & 15) == 0) {
            int h = ln >> 4;
            esT[(b * 4 + h) * NPAD + n] = ts;
            edT[(b * 4 + h) * NPAD + n] = td;
        }
    }
}

// ---------------------------------------------------------------------------
// GAT aggregation, flash-style MFMA (round 5, verified).
// ---------------------------------------------------------------------------
__global__ __launch_bounds__(512) void gat_agg(
    const __bf16* __restrict__ hpT, const float* __restrict__ esT,
    const float* __restrict__ edT, const unsigned int* __restrict__ mask,
    float* __restrict__ hout)
{
    __shared__ float Ss[8][16];

    int tid  = threadIdx.x;
    int wv   = tid >> 6;
    int lane = tid & 63;
    int l15  = lane & 15;
    int qd   = lane >> 4;
    int hh   = wv & 3;
    int ig   = wv >> 2;
    int b    = blockIdx.x / 47;
    int it   = (blockIdx.x % 47) * 32 + ig * 16;

    const __bf16* Brow = hpT + (((b << 6) + (hh << 4) + l15) * NPAD);
    const float* edrow = edT + (b * 4 + hh) * NPAD;
    const unsigned int* mrow = mask + (it + l15) * 48;
    float esv = esT[(b * 4 + hh) * NPAD + it + l15];

    f32x4 acc = {0.f, 0.f, 0.f, 0.f};
    float S = 0.f;

    for (int jt = 0; jt < 12; ++jt) {
        uint4 mw = *(const uint4*)&mrow[jt * 4];
        #pragma unroll
        for (int kt = 0; kt < 4; ++kt) {
            int jk = jt * 128 + kt * 32 + qd * 8;
            float4 e0 = *(const float4*)&edrow[jk];
            float4 e1 = *(const float4*)&edrow[jk + 4];
            unsigned int mb = ((&mw.x)[kt] >> (qd * 8)) & 0xffu;
            float ej[8] = {e0.x, e0.y, e0.z, e0.w, e1.x, e1.y, e1.z, e1.w};
            bf16x8 A;
            #pragma unroll
            for (int jj = 0; jj < 8; ++jj) {
                float e = esv + ej[jj];
                e = fmaxf(e, 0.2f * e);
                float p = ((mb >> jj) & 1u) ? __expf(e) : 0.f;
                S += p;
                A[jj] = (__bf16)p;
            }
            bf16x8 B = *(const bf16x8*)&Brow[jk];
            acc = __builtin_amdgcn_mfma_f32_16x16x32_bf16(A, B, acc, 0, 0, 0);
        }
    }

    S += __shfl_xor(S, 16);
    S += __shfl_xor(S, 32);
    if (qd == 0) Ss[wv][l15] = S;
    __syncthreads();

    #pragma unroll
    for (int r = 0; r < 4; ++r) {
        int i = it + qd * 4 + r;
        if (i < NNODE) {
            float rs = 1.f / Ss[wv][qd * 4 + r];
            hout[((b * NNODE + i) << 6) + (hh << 4) + l15] = fmaxf(acc[r] * rs, 0.f);
        }
    }
}

// ---------------------------------------------------------------------------
// Output head, coalesced: 4 lanes per node (k-split 16 each), shuffle-reduce.
// ---------------------------------------------------------------------------
__global__ __launch_bounds__(256) void out_kernel(
    const float* __restrict__ h, const float* __restrict__ oW,
    const float* __restrict__ ob, float* __restrict__ out)
{
    __shared__ float oWs[192];
    __shared__ float obs[3];
    int tid = threadIdx.x;
    if (tid < 192) oWs[tid] = oW[tid];
    if (tid < 3)   obs[tid] = ob[tid];
    __syncthreads();

    int g = blockIdx.x * 256 + tid;
    int node = g >> 2;
    int ks   = g & 3;
    if (node >= BN) return;

    float hv[16];
    const float* hr = h + node * 64 + ks * 16;
    *(float4*)&hv[0]  = *(const float4*)&hr[0];
    *(float4*)&hv[4]  = *(const float4*)&hr[4];
    *(float4*)&hv[8]  = *(const float4*)&hr[8];
    *(float4*)&hv[12] = *(const float4*)&hr[12];

    float a0 = 0.f, a1 = 0.f, a2 = 0.f;
    #pragma unroll
    for (int kk = 0; kk < 16; ++kk) {
        int k = ks * 16 + kk;
        float xv = hv[kk];
        a0 = fmaf(xv, oWs[k], a0);
        a1 = fmaf(xv, oWs[64 + k], a1);
        a2 = fmaf(xv, oWs[128 + k], a2);
    }
    a0 += __shfl_xor(a0, 1); a0 += __shfl_xor(a0, 2);
    a1 += __shfl_xor(a1, 1); a1 += __shfl_xor(a1, 2);
    a2 += __shfl_xor(a2, 1); a2 += __shfl_xor(a2, 2);
    if (ks == 0) {
        int b = node / NNODE, n = node - b * NNODE;
        float* o = out + (long)b * 3 * NNODE + n;
        o[0]         = a0 + obs[0];
        o[NNODE]     = a1 + obs[1];
        o[2 * NNODE] = a2 + obs[2];
    }
}

// ---------------------------------------------------------------------------
extern "C" void kernel_launch(void* const* d_in, const int* in_sizes, int n_in,
                              void* d_out, int out_size, void* d_ws, size_t ws_size,
                              hipStream_t stream) {
    const float* x    = (const float*)d_in[0];
    const int*   adj  = (const int*)d_in[1];
    const float* Wih0 = (const float*)d_in[2];
    const float* Whh0 = (const float*)d_in[3];
    const float* bih0 = (const float*)d_in[4];
    const float* bhh0 = (const float*)d_in[5];
    const float* Wih1 = (const float*)d_in[6];
    const float* Whh1 = (const float*)d_in[7];
    const float* bih1 = (const float*)d_in[8];
    const float* bhh1 = (const float*)d_in[9];
    const float* g0W  = (const float*)d_in[10];
    const float* g0s  = (const float*)d_in[11];
    const float* g0d  = (const float*)d_in[12];
    const float* g1W  = (const float*)d_in[13];
    const float* g1s  = (const float*)d_in[14];
    const float* g1d  = (const float*)d_in[15];
    const float* oW   = (const float*)d_in[16];
    const float* ob   = (const float*)d_in[17];

    float* ws = (float*)d_ws;
    float*        bufh  = ws;                              // 768000 f32
    float*        esT   = ws + 768000;                     // 49152
    float*        edT   = ws + 817152;                     // 49152
    __bf16*       hpT   = (__bf16*)(ws + 866304);          // 512*1536 bf16
    unsigned int* maskp = (unsigned int*)(ws + 1259520);   // 72192 u32
    __bf16*       wb0   = (__bf16*)(ws + 1331712);         // 16384 bf16
    __bf16*       wb1   = (__bf16*)(ws + 1339904);         // 32768 bf16

    wconv_kernel<<<192, 256, 0, stream>>>(Whh0, Wih1, Whh1, wb0, wb1);
    lstm_mfma<<<250, 512, 0, stream>>>(x, Wih0, bih0, bhh0, bih1, bhh1,
                                       wb0, wb1, bufh);
    mask_kernel<<<9024, 256, 0, stream>>>(adj, maskp);
    gat_prep<<<750, 256, 0, stream>>>(bufh, g0W, g0s, g0d, hpT, esT, edT);
    gat_agg<<<376, 512, 0, stream>>>(hpT, esT, edT, maskp, bufh);
    gat_prep<<<750, 256, 0, stream>>>(bufh, g1W, g1s, g1d, hpT, esT, edT);
    gat_agg<<<376, 512, 0, stream>>>(hpT, esT, edT, maskp, bufh);
    out_kernel<<<188, 256, 0, stream>>>(bufh, oW, ob, (float*)d_out);
}

// Round 9
// 231.606 us; speedup vs baseline: 10.5974x; 1.1598x over previous
//
#include <hip/hip_runtime.h>
#include <hip/hip_bf16.h>

// GATPredictor: x(8,12,1500) f32 -> 2-layer LSTM(hid64) per (b,n) sequence ->
// 2x GAT(4 heads x 16) over N=1500 graph -> linear head (3) -> (B,3,N) f32.
// LSTM: merged-phase MFMA + rcp activations (round 7, verified 46.6 us).
// gat_prep: MFMA + LDS-transpose -> coalesced hpT stores (was 2-B scattered).
// gat_agg: flash-style MFMA, exp2 with prescaled logits; final call fuses the
// output head (out_kernel removed). Setup (weight cvt + adjacency bitmask) is
// one kernel. 6 launches total.

#define BN 12000
#define NNODE 1500
#define NB 8
#define TT 12
#define NPAD 1536   // padded j extent for hpT/esT/edT rows
#define SEQB 48     // sequences per LSTM block (250 blocks exactly)
#define LOG2E 1.44269504f

typedef __bf16 bf16x8 __attribute__((ext_vector_type(8)));
typedef __bf16 bf16x4 __attribute__((ext_vector_type(4)));
typedef float  f32x4  __attribute__((ext_vector_type(4)));

// fast activations: v_rcp_f32 (~1 ulp). exp overflow -> inf -> rcp -> 0 gives
// the correct saturation limit, so no branches needed.
__device__ __forceinline__ float rcpf(float v) { return __builtin_amdgcn_rcpf(v); }
__device__ __forceinline__ float exp2f_(float v) { return __builtin_amdgcn_exp2f(v); }
__device__ __forceinline__ float sigf(float v) { return rcpf(1.f + __expf(-v)); }
__device__ __forceinline__ float tanhf_(float v) {
    return fmaf(2.f, rcpf(1.f + __expf(-2.f * v)), -1.f);
}

// ---------------------------------------------------------------------------
// Setup: bf16 weight conversions (blocks 0..223) + adjacency bitmask
// (blocks 224..9247). mask[i][w] bits j in [w*32,w*32+32); 1504 x 48 words.
// ---------------------------------------------------------------------------
__global__ __launch_bounds__(256) void setup_kernel(
    const float* __restrict__ Whh0, const float* __restrict__ Wih1,
    const float* __restrict__ Whh1, const float* __restrict__ g0W,
    const float* __restrict__ g1W, const int* __restrict__ adj,
    __bf16* __restrict__ wb0, __bf16* __restrict__ wb1,
    __bf16* __restrict__ gw0, __bf16* __restrict__ gw1,
    unsigned int* __restrict__ mask)
{
    if (blockIdx.x < 224) {
        int i = blockIdx.x * 256 + threadIdx.x;
        if (i < 16384) {
            wb0[i] = (__bf16)Whh0[i];
        } else if (i < 49152) {
            int j = i - 16384;
            int g = j >> 7, k = j & 127;
            wb1[j] = (__bf16)(k < 64 ? Wih1[(g << 6) + k] : Whh1[(g << 6) + k - 64]);
        } else if (i < 53248) {
            gw0[i - 49152] = (__bf16)g0W[i - 49152];
        } else if (i < 57344) {
            gw1[i - 53248] = (__bf16)g1W[i - 53248];
        }
    } else {
        int idx  = (blockIdx.x - 224) * 4 + (threadIdx.x >> 6);
        int lane = threadIdx.x & 63;
        int i  = idx / 24;
        int ch = idx - i * 24;
        if (i >= 1504) return;
        int j = ch * 64 + lane;
        int a = (i < NNODE && j < NNODE) ? adj[i * NNODE + j] : 0;
        unsigned long long m = __ballot(a > 0);
        if (lane == 0) *(unsigned long long*)&mask[i * 48 + ch * 2] = m;
    }
}

// ---------------------------------------------------------------------------
// Merged-phase MFMA 2-layer LSTM (round-7 structure, verified).
// Block = 48 seqs, 512 thr (8 waves). 2 barriers/step.
// ---------------------------------------------------------------------------
__global__ __launch_bounds__(512, 1) void lstm_mfma(
    const float* __restrict__ x,
    const float* __restrict__ Wih0,
    const float* __restrict__ bih0, const float* __restrict__ bhh0,
    const float* __restrict__ bih1, const float* __restrict__ bhh1,
    const __bf16* __restrict__ wb0, const __bf16* __restrict__ wb1,
    float* __restrict__ hfin)
{
    __shared__ __align__(16) __bf16 h0s[SEQB * 72];   // 6.75 KB
    __shared__ __align__(16) __bf16 h1s[SEQB * 72];   // 6.75 KB
    __shared__ __align__(16) float  xls[TT * SEQB];   // 2.25 KB

    int tid  = threadIdx.x;
    int w    = __builtin_amdgcn_readfirstlane(tid >> 6);
    int lane = tid & 63;
    int l15  = lane & 15;
    int qd   = lane >> 4;
    bool lo  = l15 < 8;
    int dloc = l15 & 7;
    int d    = 8 * w + dloc;

    for (int e = tid; e < (SEQB * 72) / 2; e += 512) ((unsigned int*)h1s)[e] = 0u;
    for (int e = tid; e < TT * SEQB; e += 512) {
        int t = e / SEQB, m = e - t * SEQB;
        int s = blockIdx.x * SEQB + m;
        int bb = s / NNODE, nn = s - bb * NNODE;
        xls[e] = x[bb * (TT * NNODE) + t * NNODE + nn];
    }

    int gA = (lo ? 0 : 64) + d;
    int gB = (lo ? 128 : 192) + d;
    bf16x8 B0A[2], B0B[2], B1A[4], B1B[4];
    #pragma unroll
    for (int kt = 0; kt < 2; ++kt) {
        B0A[kt] = *(const bf16x8*)&wb0[gA * 64 + 32 * kt + 8 * qd];
        B0B[kt] = *(const bf16x8*)&wb0[gB * 64 + 32 * kt + 8 * qd];
    }
    #pragma unroll
    for (int kt = 0; kt < 4; ++kt) {
        B1A[kt] = *(const bf16x8*)&wb1[gA * 128 + 32 * kt + 8 * qd];
        B1B[kt] = *(const bf16x8*)&wb1[gB * 128 + 32 * kt + 8 * qd];
    }
    float b0A = bih0[gA] + bhh0[gA], b0B = bih0[gB] + bhh0[gB];
    float b1A = bih1[gA] + bhh1[gA], b1B = bih1[gB] + bhh1[gB];
    float w0A = Wih0[gA], w0B = Wih0[gB];

    float pwi = Wih0[d],       pbi = bih0[d]       + bhh0[d];
    float pwg = Wih0[128 + d], pbg = bih0[128 + d] + bhh0[128 + d];
    float pwo = Wih0[192 + d], pbo = bih0[192 + d] + bhh0[192 + d];

    float c0[3][2], c1[3][2];
    #pragma unroll
    for (int mt = 0; mt < 3; ++mt) { c0[mt][0] = c0[mt][1] = c1[mt][0] = c1[mt][1] = 0.f; }

    __syncthreads();

    #pragma unroll
    for (int mt = 0; mt < 3; ++mt)
        #pragma unroll
        for (int rl = 0; rl < 2; ++rl) {
            int rr = lo ? rl : 2 + rl;
            int m = 16 * mt + 4 * qd + rr;
            float xv = xls[m];
            float gi = fmaf(pwi, xv, pbi);
            float gg = fmaf(pwg, xv, pbg);
            float go = fmaf(pwo, xv, pbo);
            float c = sigf(gi) * tanhf_(gg);
            c0[mt][rl] = c;
            h0s[m * 72 + d] = (__bf16)(sigf(go) * tanhf_(c));
        }
    __syncthreads();

    for (int t = 0; t < TT; ++t) {
        bool last = (t == TT - 1);
        bf16x8 a0[3][2], a1[3][2];
        #pragma unroll
        for (int mt = 0; mt < 3; ++mt)
            #pragma unroll
            for (int kt = 0; kt < 2; ++kt) {
                a0[mt][kt] = *(bf16x8*)&h0s[(16 * mt + l15) * 72 + 32 * kt + 8 * qd];
                a1[mt][kt] = *(bf16x8*)&h1s[(16 * mt + l15) * 72 + 32 * kt + 8 * qd];
            }
        f32x4 AA1[3], AB1[3], AA0[3], AB0[3];
        #pragma unroll
        for (int mt = 0; mt < 3; ++mt) {
            #pragma unroll
            for (int r = 0; r < 4; ++r) { AA1[mt][r] = b1A; AB1[mt][r] = b1B; }
            if (!last) {
                f32x4 xv = *(f32x4*)&xls[(t + 1) * SEQB + 16 * mt + 4 * qd];
                #pragma unroll
                for (int r = 0; r < 4; ++r) {
                    AA0[mt][r] = fmaf(w0A, xv[r], b0A);
                    AB0[mt][r] = fmaf(w0B, xv[r], b0B);
                }
            }
        }
        #pragma unroll
        for (int mt = 0; mt < 3; ++mt) {
            #pragma unroll
            for (int kt = 0; kt < 2; ++kt) {
                AA1[mt] = __builtin_amdgcn_mfma_f32_16x16x32_bf16(a0[mt][kt], B1A[kt], AA1[mt], 0, 0, 0);
                AB1[mt] = __builtin_amdgcn_mfma_f32_16x16x32_bf16(a0[mt][kt], B1B[kt], AB1[mt], 0, 0, 0);
                AA1[mt] = __builtin_amdgcn_mfma_f32_16x16x32_bf16(a1[mt][kt], B1A[kt + 2], AA1[mt], 0, 0, 0);
                AB1[mt] = __builtin_amdgcn_mfma_f32_16x16x32_bf16(a1[mt][kt], B1B[kt + 2], AB1[mt], 0, 0, 0);
            }
            if (!last) {
                #pragma unroll
                for (int kt = 0; kt < 2; ++kt) {
                    AA0[mt] = __builtin_amdgcn_mfma_f32_16x16x32_bf16(a0[mt][kt], B0A[kt], AA0[mt], 0, 0, 0);
                    AB0[mt] = __builtin_amdgcn_mfma_f32_16x16x32_bf16(a0[mt][kt], B0B[kt], AB0[mt], 0, 0, 0);
                }
            }
        }
        __syncthreads();

        #pragma unroll
        for (int mt = 0; mt < 3; ++mt) {
            {
                float shA0 = __shfl_xor(lo ? AA1[mt][2] : AA1[mt][0], 8);
                float shA1 = __shfl_xor(lo ? AA1[mt][3] : AA1[mt][1], 8);
                float shB0 = __shfl_xor(lo ? AB1[mt][2] : AB1[mt][0], 8);
                float shB1 = __shfl_xor(lo ? AB1[mt][3] : AB1[mt][1], 8);
                #pragma unroll
                for (int rl = 0; rl < 2; ++rl) {
                    int rr = lo ? rl : 2 + rl;
                    float ownA = AA1[mt][rr], ownB = AB1[mt][rr];
                    float shA = rl ? shA1 : shA0, shB = rl ? shB1 : shB0;
                    float gi = lo ? ownA : shA;
                    float gf = lo ? shA : ownA;
                    float gg = lo ? ownB : shB;
                    float go = lo ? shB : ownB;
                    float c = sigf(gf) * c1[mt][rl] + sigf(gi) * tanhf_(gg);
                    c1[mt][rl] = c;
                    float hv = sigf(go) * tanhf_(c);
                    int m = 16 * mt + 4 * qd + rr;
                    if (!last) h1s[m * 72 + d] = (__bf16)hv;
                    else       hfin[(blockIdx.x * SEQB + m) * 64 + d] = hv;
                }
            }
            if (!last) {
                float shA0 = __shfl_xor(lo ? AA0[mt][2] : AA0[mt][0], 8);
                float shA1 = __shfl_xor(lo ? AA0[mt][3] : AA0[mt][1], 8);
                float shB0 = __shfl_xor(lo ? AB0[mt][2] : AB0[mt][0], 8);
                float shB1 = __shfl_xor(lo ? AB0[mt][3] : AB0[mt][1], 8);
                #pragma unroll
                for (int rl = 0; rl < 2; ++rl) {
                    int rr = lo ? rl : 2 + rl;
                    float ownA = AA0[mt][rr], ownB = AB0[mt][rr];
                    float shA = rl ? shA1 : shA0, shB = rl ? shB1 : shB0;
                    float gi = lo ? ownA : shA;
                    float gf = lo ? shA : ownA;
                    float gg = lo ? ownB : shB;
                    float go = lo ? shB : ownB;
                    float c = sigf(gf) * c0[mt][rl] + sigf(gi) * tanhf_(gg);
                    c0[mt][rl] = c;
                    int m = 16 * mt + 4 * qd + rr;
                    h0s[m * 72 + d] = (__bf16)(sigf(go) * tanhf_(c));
                }
            }
        }
        __syncthreads();
    }
}

// ---------------------------------------------------------------------------
// GAT projection, MFMA: hpT[b*64+d][n] = (h @ W.T)^T  (bf16), plus
// esT/edT[b*4+h][n] pre-scaled by log2(e). Block = 64 nodes, 4 waves x 16.
// A = W rows (bf16, preconverted), B = h fragments (f32 -> bf16 cvt).
// C[col=node][row=dim] staged to LDS [64 dim][72] -> coalesced row stores.
// ---------------------------------------------------------------------------
__global__ __launch_bounds__(256) void gat_prep(
    const float* __restrict__ hin, const __bf16* __restrict__ Wb,
    const float* __restrict__ asrc, const float* __restrict__ adst,
    __bf16* __restrict__ hpT, float* __restrict__ esT, float* __restrict__ edT)
{
    __shared__ __align__(16) __bf16 hp_t[64 * 72];   // [dim][node] 9 KB
    __shared__ float avs[128];

    int tid  = threadIdx.x;
    int wv   = tid >> 6;
    int lane = tid & 63;
    int l15  = lane & 15;
    int qd   = lane >> 4;

    if (tid < 64)       avs[tid] = asrc[tid] * LOG2E;
    else if (tid < 128) avs[tid] = adst[tid - 64] * LOG2E;

    int s0 = blockIdx.x * 64;
    int sn = s0 + wv * 16 + l15;
    int snc = min(sn, BN - 1);

    // B-fragments: B[n=l15][k=qd*8+j], two K-halves
    bf16x8 Bf[2];
    #pragma unroll
    for (int kt = 0; kt < 2; ++kt) {
        f32x4 ha = *(const f32x4*)&hin[snc * 64 + kt * 32 + qd * 8];
        f32x4 hb = *(const f32x4*)&hin[snc * 64 + kt * 32 + qd * 8 + 4];
        bf16x8 bv;
        #pragma unroll
        for (int r = 0; r < 4; ++r) { bv[r] = (__bf16)ha[r]; bv[4 + r] = (__bf16)hb[r]; }
        Bf[kt] = bv;
    }
    __syncthreads();   // avs ready

    f32x4 acc[4];
    #pragma unroll
    for (int mt = 0; mt < 4; ++mt) {
        int dd = mt * 16 + l15;
        bf16x8 A0 = *(const bf16x8*)&Wb[dd * 64 + qd * 8];
        bf16x8 A1 = *(const bf16x8*)&Wb[dd * 64 + 32 + qd * 8];
        f32x4 a = {0.f, 0.f, 0.f, 0.f};
        a = __builtin_amdgcn_mfma_f32_16x16x32_bf16(A0, Bf[0], a, 0, 0, 0);
        a = __builtin_amdgcn_mfma_f32_16x16x32_bf16(A1, Bf[1], a, 0, 0, 0);
        acc[mt] = a;
    }

    // es/ed per head (head == mt) + stage hp into LDS transposed
    #pragma unroll
    for (int mt = 0; mt < 4; ++mt) {
        float ts = 0.f, td = 0.f;
        #pragma unroll
        for (int r = 0; r < 4; ++r) {
            int dd = mt * 16 + qd * 4 + r;
            ts = fmaf(acc[mt][r], avs[dd], ts);
            td = fmaf(acc[mt][r], avs[64 + dd], td);
            hp_t[dd * 72 + wv * 16 + l15] = (__bf16)acc[mt][r];
        }
        ts += __shfl_xor(ts, 16); ts += __shfl_xor(ts, 32);
        td += __shfl_xor(td, 16); td += __shfl_xor(td, 32);
        if (qd == 0 && sn < BN) {
            int b = sn / NNODE, n = sn - b * NNODE;
            esT[(b * 4 + mt) * NPAD + n] = ts;
            edT[(b * 4 + mt) * NPAD + n] = td;
        }
    }
    __syncthreads();

    // write-out: rows of 64 nodes, coalesced (fast path when block is in one b)
    int dim = tid >> 2, seg = tid & 3;
    int b0 = s0 / NNODE, b1 = (s0 + 63) / NNODE;
    if (b0 == b1 && s0 + 63 < BN) {
        int n0 = s0 - b0 * NNODE;   // multiple of 4 -> 8-B aligned stores
        bf16x4 v0 = *(bf16x4*)&hp_t[dim * 72 + seg * 16];
        bf16x4 v1 = *(bf16x4*)&hp_t[dim * 72 + seg * 16 + 4];
        bf16x4 v2 = *(bf16x4*)&hp_t[dim * 72 + seg * 16 + 8];
        bf16x4 v3 = *(bf16x4*)&hp_t[dim * 72 + seg * 16 + 12];
        __bf16* dst = &hpT[((b0 << 6) + dim) * NPAD + n0 + seg * 16];
        *(bf16x4*)(dst)      = v0;
        *(bf16x4*)(dst + 4)  = v1;
        *(bf16x4*)(dst + 8)  = v2;
        *(bf16x4*)(dst + 12) = v3;
    } else {
        #pragma unroll
        for (int u = 0; u < 16; ++u) {
            int ss = s0 + seg * 16 + u;
            if (ss < BN) {
                int b = ss / NNODE, n = ss - b * NNODE;
                hpT[((b << 6) + dim) * NPAD + n] = hp_t[dim * 72 + seg * 16 + u];
            }
        }
    }
}

// ---------------------------------------------------------------------------
// GAT aggregation, flash-style MFMA. esT/edT are pre-scaled by log2(e) so
// p = exp2(leaky(es'+ed')) (leaky commutes with positive scaling).
// final=1: skip hout, fuse the 3-wide output head (block holds all 64 dims
// of its 32 nodes) and write d_out directly.
// ---------------------------------------------------------------------------
__global__ __launch_bounds__(512) void gat_agg(
    const __bf16* __restrict__ hpT, const float* __restrict__ esT,
    const float* __restrict__ edT, const unsigned int* __restrict__ mask,
    float* __restrict__ hout, const float* __restrict__ oW,
    const float* __restrict__ ob, float* __restrict__ outp, int final)
{
    __shared__ float Ss[8][16];
    __shared__ float hbuf[32 * 72];   // 9 KB (final path)
    __shared__ float oWs[192];
    __shared__ float obs[3];

    int tid  = threadIdx.x;
    int wv   = tid >> 6;
    int lane = tid & 63;
    int l15  = lane & 15;
    int qd   = lane >> 4;
    int hh   = wv & 3;
    int ig   = wv >> 2;
    int b    = blockIdx.x / 47;
    int i0   = (blockIdx.x % 47) * 32;
    int it   = i0 + ig * 16;

    if (final) {
        if (tid < 192) oWs[tid] = oW[tid];
        if (tid < 3)   obs[tid] = ob[tid];
    }

    const __bf16* Brow = hpT + (((b << 6) + (hh << 4) + l15) * NPAD);
    const float* edrow = edT + (b * 4 + hh) * NPAD;
    const unsigned int* mrow = mask + (it + l15) * 48;
    float esv = esT[(b * 4 + hh) * NPAD + it + l15];

    f32x4 acc = {0.f, 0.f, 0.f, 0.f};
    float S = 0.f;

    for (int jt = 0; jt < 12; ++jt) {
        uint4 mw = *(const uint4*)&mrow[jt * 4];
        #pragma unroll
        for (int kt = 0; kt < 4; ++kt) {
            int jk = jt * 128 + kt * 32 + qd * 8;
            float4 e0 = *(const float4*)&edrow[jk];
            float4 e1 = *(const float4*)&edrow[jk + 4];
            unsigned int mb = ((&mw.x)[kt] >> (qd * 8)) & 0xffu;
            float ej[8] = {e0.x, e0.y, e0.z, e0.w, e1.x, e1.y, e1.z, e1.w};
            bf16x8 A;
            #pragma unroll
            for (int jj = 0; jj < 8; ++jj) {
                float e = esv + ej[jj];
                e = fmaxf(e, 0.2f * e);
                float p = ((mb >> jj) & 1u) ? exp2f_(e) : 0.f;
                S += p;
                A[jj] = (__bf16)p;
            }
            bf16x8 B = *(const bf16x8*)&Brow[jk];
            acc = __builtin_amdgcn_mfma_f32_16x16x32_bf16(A, B, acc, 0, 0, 0);
        }
    }

    S += __shfl_xor(S, 16);
    S += __shfl_xor(S, 32);
    if (qd == 0) Ss[wv][l15] = S;
    __syncthreads();

    if (!final) {
        #pragma unroll
        for (int r = 0; r < 4; ++r) {
            int i = it + qd * 4 + r;
            if (i < NNODE) {
                float rs = rcpf(Ss[wv][qd * 4 + r]);
                hout[((b * NNODE + i) << 6) + (hh << 4) + l15] = fmaxf(acc[r] * rs, 0.f);
            }
        }
    } else {
        #pragma unroll
        for (int r = 0; r < 4; ++r) {
            float rs = rcpf(Ss[wv][qd * 4 + r]);
            hbuf[(ig * 16 + qd * 4 + r) * 72 + (hh << 4) + l15] = fmaxf(acc[r] * rs, 0.f);
        }
        __syncthreads();
        if (tid < 384) {
            int idx = tid >> 2, ks = tid & 3;
            int nl = idx & 31, o = idx >> 5;
            if (i0 + nl < NNODE) {
                const float* hb = &hbuf[nl * 72 + ks * 16];
                float a = 0.f;
                #pragma unroll
                for (int kk = 0; kk < 16; ++kk)
                    a = fmaf(hb[kk], oWs[o * 64 + ks * 16 + kk], a);
                a += __shfl_xor(a, 1);
                a += __shfl_xor(a, 2);
                if (ks == 0)
                    outp[(long)b * 3 * NNODE + o * NNODE + i0 + nl] = a + obs[o];
            }
        }
    }
}

// ---------------------------------------------------------------------------
extern "C" void kernel_launch(void* const* d_in, const int* in_sizes, int n_in,
                              void* d_out, int out_size, void* d_ws, size_t ws_size,
                              hipStream_t stream) {
    const float* x    = (const float*)d_in[0];
    const int*   adj  = (const int*)d_in[1];
    const float* Wih0 = (const float*)d_in[2];
    const float* Whh0 = (const float*)d_in[3];
    const float* bih0 = (const float*)d_in[4];
    const float* bhh0 = (const float*)d_in[5];
    const float* Wih1 = (const float*)d_in[6];
    const float* Whh1 = (const float*)d_in[7];
    const float* bih1 = (const float*)d_in[8];
    const float* bhh1 = (const float*)d_in[9];
    const float* g0W  = (const float*)d_in[10];
    const float* g0s  = (const float*)d_in[11];
    const float* g0d  = (const float*)d_in[12];
    const float* g1W  = (const float*)d_in[13];
    const float* g1s  = (const float*)d_in[14];
    const float* g1d  = (const float*)d_in[15];
    const float* oW   = (const float*)d_in[16];
    const float* ob   = (const float*)d_in[17];

    float* ws = (float*)d_ws;
    float*        bufh  = ws;                              // 768000 f32
    float*        esT   = ws + 768000;                     // 49152
    float*        edT   = ws + 817152;                     // 49152
    __bf16*       hpT   = (__bf16*)(ws + 866304);          // 512*1536 bf16
    unsigned int* maskp = (unsigned int*)(ws + 1259520);   // 72192 u32
    __bf16*       wb0   = (__bf16*)(ws + 1331712);         // 16384 bf16
    __bf16*       wb1   = (__bf16*)(ws + 1339904);         // 32768 bf16
    __bf16*       gw0   = (__bf16*)(ws + 1356288);         // 4096 bf16
    __bf16*       gw1   = (__bf16*)(ws + 1358336);         // 4096 bf16

    setup_kernel<<<9248, 256, 0, stream>>>(Whh0, Wih1, Whh1, g0W, g1W, adj,
                                           wb0, wb1, gw0, gw1, maskp);
    lstm_mfma<<<250, 512, 0, stream>>>(x, Wih0, bih0, bhh0, bih1, bhh1,
                                       wb0, wb1, bufh);
    gat_prep<<<188, 256, 0, stream>>>(bufh, gw0, g0s, g0d, hpT, esT, edT);
    gat_agg<<<376, 512, 0, stream>>>(hpT, esT, edT, maskp, bufh,
                                     oW, ob, (float*)d_out, 0);
    gat_prep<<<188, 256, 0, stream>>>(bufh, gw1, g1s, g1d, hpT, esT, edT);
    gat_agg<<<376, 512, 0, stream>>>(hpT, esT, edT, maskp, bufh,
                                     oW, ob, (float*)d_out, 1);
}